// Round 16
// baseline (130.132 us; speedup 1.0000x reference)
//
#include <hip/hip_runtime.h>
#include <hip/hip_fp16.h>

typedef _Float16 f16x8 __attribute__((ext_vector_type(8)));
typedef _Float16 f16x2 __attribute__((ext_vector_type(2)));
typedef float f32x4 __attribute__((ext_vector_type(4)));

#define NPB 256      // nodes per bucket (dst >> 8)
#define FCHUNK 6144  // edges per fill block (6 per thread @ 1024 threads)
#define MAXBK 512    // LDS bucket array size (>= NBUCK=391)
#define CAPP 5120    // static packed capacity per bucket (mean 4092, sigma 64)
#define CAP8 6144    // static padded-csr capacity per bucket

// fused prep: [0,XGRID) x fp32->fp16; [XGRID,+24) weight fragments;
// XGRID+24: c2 + zero row N; XGRID+25: cursor/stats init
__global__ __launch_bounds__(256) void k_prep(
    const float4* __restrict__ x4, __half2* __restrict__ xh2, int n4, int XGRID,
    const float* __restrict__ We, const float* __restrict__ be,
    const float* __restrict__ Wn, __half* __restrict__ Wfrag, float* __restrict__ c2,
    int* __restrict__ cur, float* __restrict__ stats, int nbuck, int N) {
  int b = blockIdx.x, t = threadIdx.x;
  if (b < XGRID) {
    int i = b * 256 + t;
    if (i < n4) {
      float4 v = x4[i];
      __half2 a, c;
      a.x = __float2half_rn(v.x); a.y = __float2half_rn(v.y);
      c.x = __float2half_rn(v.z); c.y = __float2half_rn(v.w);
      xh2[2 * i] = a;
      xh2[2 * i + 1] = c;
    }
  } else {
    int mb = b - XGRID;
    if (mb < 24) {
      int mat = mb >> 3, kk = (mb >> 2) & 1, ct = mb & 3;
      for (int tt = t; tt < 512; tt += 256) {
        int lane = tt >> 3, j = tt & 7;
        int k = kk * 32 + ((lane >> 4) & 3) * 8 + j;
        int col = ct * 16 + (lane & 15);
        float v;
        if (mat == 0) {
          v = Wn[k * 64 + col];
        } else if (mat == 1) {
          float a = 0.f;
          for (int m = 0; m < 64; ++m) a += We[k * 64 + m] * Wn[(64 + m) * 64 + col];
          v = a;
        } else {
          float a = 0.f;
          for (int m = 0; m < 64; ++m) a += We[(64 + k) * 64 + m] * Wn[(64 + m) * 64 + col];
          v = a;
        }
        Wfrag[mb * 512 + tt] = __float2half_rn(v);
      }
    } else if (mb == 24) {
      if (t < 64) {
        float a = 0.f;
        for (int m = 0; m < 64; ++m) a += be[m] * Wn[(64 + m) * 64 + t];
        c2[t] = a;
      } else if (t < 96) {
        __half2 z; z.x = __float2half_rn(0.f); z.y = __float2half_rn(0.f);
        xh2[(size_t)N * 32 + (t - 64)] = z;   // zero row N (pad target)
      }
    } else {
      for (int i = t; i < nbuck; i += 256) cur[i] = i * CAPP;
      if (t < 128) stats[t] = 0.f;
    }
  }
}

// scatter edges into static bucket segments; 1024 threads/block for occupancy
__global__ __launch_bounds__(1024) void k_fill3(const int* __restrict__ src,
    const int* __restrict__ dst, int* __restrict__ cur,
    int* __restrict__ packed, int E) {
  __shared__ int lh[MAXBK];
  __shared__ int gbase[MAXBK];
  int t = threadIdx.x;
  int e0 = blockIdx.x * FCHUNK;
  int e1 = min(e0 + FCHUNK, E);
  for (int i = t; i < MAXBK; i += 1024) lh[i] = 0;
  __syncthreads();
  int dv[6];
#pragma unroll
  for (int i = 0; i < 6; ++i) {
    int e = e0 + t + i * 1024;
    dv[i] = (e < e1) ? dst[e] : -1;
    if (dv[i] >= 0) atomicAdd(&lh[dv[i] >> 8], 1);
  }
  __syncthreads();
  for (int i = t; i < MAXBK; i += 1024) {
    int c = lh[i];
    gbase[i] = c ? atomicAdd(&cur[i], c) : 0;
    lh[i] = 0;  // reuse as local cursor
  }
  __syncthreads();
#pragma unroll
  for (int i = 0; i < 6; ++i) {
    int d = dv[i];
    if (d >= 0) {
      int e = e0 + t + i * 1024;
      int bk = d >> 8;
      int lp = atomicAdd(&lh[bk], 1);
      packed[gbase[bk] + lp] = src[e] | ((d & 255) << 20);
    }
  }
}

// per-bucket counting sort -> 8-PADDED per-node CSR (pads point at zero row N)
__global__ __launch_bounds__(256) void k_sort(const int* __restrict__ packed,
    const int* __restrict__ cur, int* __restrict__ csr,
    int* __restrict__ offA, int* __restrict__ deg, int N) {
  __shared__ int hist[NPB];
  __shared__ int sc[NPB];
  __shared__ int curs[NPB];
  int b = blockIdx.x, t = threadIdx.x;
  hist[t] = 0;
  __syncthreads();
  int e0 = b * CAPP;
  int e1 = cur[b];             // end of this bucket's real edges
  for (int e = e0 + t; e < e1; e += 256)
    atomicAdd(&hist[(packed[e] >> 20) & 255], 1);
  __syncthreads();
  int v = hist[t];
  int pv = (v + 7) & ~7;       // padded degree
  sc[t] = pv;
  __syncthreads();
  for (int d = 1; d < 256; d <<= 1) {
    int a = (t >= d) ? sc[t - d] : 0;
    __syncthreads();
    sc[t] += a;
    __syncthreads();
  }
  int ex = b * CAP8 + sc[t] - pv;   // padded CSR start for this node
  curs[t] = ex;
  int n = b * NPB + t;
  if (n < N) { offA[n] = ex; deg[n] = v; }
  __syncthreads();
  for (int e = e0 + t; e < e1; e += 256) {
    int pk = packed[e];
    int p = atomicAdd(&curs[(pk >> 20) & 255], 1);
    csr[p] = pk & 0xFFFFF;
  }
  for (int k = v; k < pv; ++k) csr[ex + k] = N;
}

// one 8-edge batch for one node: scalar csr reads + 4 dword gathers, packed fp16 acc
#define BATCH8(J0, J, ACC0, ACC1)                                              \
  {                                                                            \
    int u_ = __builtin_amdgcn_readfirstlane((J0) + (J));                       \
    int e0_ = csr[u_ + 0], e1_ = csr[u_ + 1], e2_ = csr[u_ + 2], e3_ = csr[u_ + 3]; \
    int e4_ = csr[u_ + 4], e5_ = csr[u_ + 5], e6_ = csr[u_ + 6], e7_ = csr[u_ + 7]; \
    unsigned s0_ = (unsigned)(slot ? e1_ : e0_), s1_ = (unsigned)(slot ? e3_ : e2_); \
    unsigned s2_ = (unsigned)(slot ? e5_ : e4_), s3_ = (unsigned)(slot ? e7_ : e6_); \
    f16x2 v0_ = xh2[(s0_ << 5) | f], v1_ = xh2[(s1_ << 5) | f];                \
    f16x2 v2_ = xh2[(s2_ << 5) | f], v3_ = xh2[(s3_ << 5) | f];                \
    ACC0 += v0_; ACC1 += v1_; ACC0 += v2_; ACC1 += v3_;                        \
  }

// S[n] = sum over incoming edges of x[src]. Tail-free padded CSR; QUAD-node
// interleave (16 dword gathers in flight); shfl_xor(32) slot merge.
__global__ void k_agg(const f16x2* __restrict__ xh2, const int* __restrict__ offA,
                      const int* __restrict__ deg, const int* __restrict__ csr,
                      f16x2* __restrict__ Sh2, int N) {
  int t = threadIdx.x;
  unsigned lane = t & 63;
  unsigned f = lane & 31;          // feature-pair index
  int slot = (int)(lane >> 5);     // 0/1: which edge of a pair
  int wid = (blockIdx.x * blockDim.x + t) >> 6;
  int nw = (gridDim.x * blockDim.x) >> 6;
  for (int n = wid; n < N; n += 4 * nw) {
    int nB = n + nw, nC = n + 2 * nw, nD = n + 3 * nw;
    int j0A = offA[n];
    int pdA = (deg[n] + 7) & ~7;
    int j0B = (nB < N) ? offA[nB] : 0;
    int pdB = (nB < N) ? ((deg[nB] + 7) & ~7) : 0;
    int j0C = (nC < N) ? offA[nC] : 0;
    int pdC = (nC < N) ? ((deg[nC] + 7) & ~7) : 0;
    int j0D = (nD < N) ? offA[nD] : 0;
    int pdD = (nD < N) ? ((deg[nD] + 7) & ~7) : 0;
    f16x2 aA0 = {0, 0}, aA1 = {0, 0}, aB0 = {0, 0}, aB1 = {0, 0};
    f16x2 aC0 = {0, 0}, aC1 = {0, 0}, aD0 = {0, 0}, aD1 = {0, 0};
    int jA = 0, jB = 0, jC = 0, jD = 0;
    // quad main loop: 16 gathers in flight
    for (; jA < pdA && jB < pdB && jC < pdC && jD < pdD;
         jA += 8, jB += 8, jC += 8, jD += 8) {
      BATCH8(j0A, jA, aA0, aA1)
      BATCH8(j0B, jB, aB0, aB1)
      BATCH8(j0C, jC, aC0, aC1)
      BATCH8(j0D, jD, aD0, aD1)
    }
    // pair drains (keep 8 in flight while two remain)
    for (; jA < pdA && jB < pdB; jA += 8, jB += 8) {
      BATCH8(j0A, jA, aA0, aA1)
      BATCH8(j0B, jB, aB0, aB1)
    }
    for (; jC < pdC && jD < pdD; jC += 8, jD += 8) {
      BATCH8(j0C, jC, aC0, aC1)
      BATCH8(j0D, jD, aD0, aD1)
    }
    for (; jA < pdA && jC < pdC; jA += 8, jC += 8) {
      BATCH8(j0A, jA, aA0, aA1)
      BATCH8(j0C, jC, aC0, aC1)
    }
    for (; jB < pdB && jD < pdD; jB += 8, jD += 8) {
      BATCH8(j0B, jB, aB0, aB1)
      BATCH8(j0D, jD, aD0, aD1)
    }
    // single drains
    for (; jA < pdA; jA += 8) BATCH8(j0A, jA, aA0, aA1)
    for (; jB < pdB; jB += 8) BATCH8(j0B, jB, aB0, aB1)
    for (; jC < pdC; jC += 8) BATCH8(j0C, jC, aC0, aC1)
    for (; jD < pdD; jD += 8) BATCH8(j0D, jD, aD0, aD1)
    // slot merge + store
    {
      f16x2 p = aA0 + aA1;
      unsigned u = __builtin_bit_cast(unsigned, p);
      unsigned ux = (unsigned)__shfl_xor((int)u, 32);
      f16x2 tot = p + __builtin_bit_cast(f16x2, ux);
      if (slot == 0) Sh2[((unsigned)n << 5) | f] = tot;
    }
    if (nB < N) {
      f16x2 p = aB0 + aB1;
      unsigned u = __builtin_bit_cast(unsigned, p);
      unsigned ux = (unsigned)__shfl_xor((int)u, 32);
      f16x2 tot = p + __builtin_bit_cast(f16x2, ux);
      if (slot == 0) Sh2[((unsigned)nB << 5) | f] = tot;
    }
    if (nC < N) {
      f16x2 p = aC0 + aC1;
      unsigned u = __builtin_bit_cast(unsigned, p);
      unsigned ux = (unsigned)__shfl_xor((int)u, 32);
      f16x2 tot = p + __builtin_bit_cast(f16x2, ux);
      if (slot == 0) Sh2[((unsigned)nC << 5) | f] = tot;
    }
    if (nD < N) {
      f16x2 p = aD0 + aD1;
      unsigned u = __builtin_bit_cast(unsigned, p);
      unsigned ux = (unsigned)__shfl_xor((int)u, 32);
      f16x2 tot = p + __builtin_bit_cast(f16x2, ux);
      if (slot == 0) Sh2[((unsigned)nD << 5) | f] = tot;
    }
  }
}

// node model via MFMA: h = PReLU(x@M1 + S@M2 + deg*(x@M3 + c2) + b); h -> fp16
__global__ __launch_bounds__(256) void k_nodeM(const __half* __restrict__ xh,
    const __half* __restrict__ Sh, const int* __restrict__ deg,
    const __half* __restrict__ Wfrag, const float* __restrict__ c2,
    const float* __restrict__ bnode, const float* __restrict__ pa,
    __half* __restrict__ Hh, int N) {
  const f16x8* WF = (const f16x8*)Wfrag;
  int t = threadIdx.x, lane = t & 63;
  f16x8 B[24];
#pragma unroll
  for (int f = 0; f < 24; ++f) B[f] = WF[f * 64 + lane];
  float slope = pa[0];
  int wid = (blockIdx.x * blockDim.x + t) >> 6;
  int nw = (gridDim.x * blockDim.x) >> 6;
  int ntile = N >> 4;
  int r = lane & 15, g = lane >> 4;
  for (int tile = wid; tile < ntile; tile += nw) {
    int n0 = tile << 4;
    float dg[4];
#pragma unroll
    for (int q = 0; q < 4; ++q) dg[q] = (float)deg[n0 + g * 4 + q];
    const f16x8* xp = (const f16x8*)(xh + (size_t)(n0 + r) * 64 + g * 8);
    const f16x8* sp = (const f16x8*)(Sh + (size_t)(n0 + r) * 64 + g * 8);
    f16x8 ax0 = xp[0], ax1 = xp[4];
    f16x8 as0 = sp[0], as1 = sp[4];
    f32x4 accA[4], accB[4];
#pragma unroll
    for (int ct = 0; ct < 4; ++ct) {
      f32x4 a = {0.f, 0.f, 0.f, 0.f};
      a = __builtin_amdgcn_mfma_f32_16x16x32_f16(ax0, B[0 + ct], a, 0, 0, 0);
      a = __builtin_amdgcn_mfma_f32_16x16x32_f16(ax1, B[4 + ct], a, 0, 0, 0);
      a = __builtin_amdgcn_mfma_f32_16x16x32_f16(as0, B[8 + ct], a, 0, 0, 0);
      a = __builtin_amdgcn_mfma_f32_16x16x32_f16(as1, B[12 + ct], a, 0, 0, 0);
      accA[ct] = a;
      f32x4 bb = {0.f, 0.f, 0.f, 0.f};
      bb = __builtin_amdgcn_mfma_f32_16x16x32_f16(ax0, B[16 + ct], bb, 0, 0, 0);
      bb = __builtin_amdgcn_mfma_f32_16x16x32_f16(ax1, B[20 + ct], bb, 0, 0, 0);
      accB[ct] = bb;
    }
#pragma unroll
    for (int ct = 0; ct < 4; ++ct) {
      int c = ct * 16 + r;
      float cc = c2[c], bv = bnode[c];
#pragma unroll
      for (int q = 0; q < 4; ++q) {
        float hv = accA[ct][q] + dg[q] * (accB[ct][q] + cc) + bv;
        hv = hv >= 0.f ? hv : slope * hv;
        Hh[(size_t)(n0 + g * 4 + q) * 64 + c] = __float2half_rn(hv);
      }
    }
  }
}

// column sums/sumsq over Hh: reg accumulate -> LDS atomics -> 128 global atomics/block
__global__ __launch_bounds__(256) void k_stats(const __half2* __restrict__ hh,
    float* __restrict__ stats, int n2) {
  __shared__ float ls[128];
  int t = threadIdx.x;
  if (t < 128) ls[t] = 0.f;
  __syncthreads();
  int cb = (t & 31) * 2;
  float s0 = 0.f, q0 = 0.f, s1 = 0.f, q1 = 0.f;
  int stride = gridDim.x * 256;
  for (int i = blockIdx.x * 256 + t; i < n2; i += stride) {
    __half2 v = hh[i];
    float a = __half2float(v.x), b = __half2float(v.y);
    s0 += a; q0 += a * a;
    s1 += b; q1 += b * b;
  }
  atomicAdd(&ls[cb], s0);
  atomicAdd(&ls[cb + 1], s1);
  atomicAdd(&ls[64 + cb], q0);
  atomicAdd(&ls[64 + cb + 1], q1);
  __syncthreads();
  if (t < 128) atomicAdd(&stats[t], ls[t]);
}

// BN finalize fused into the output pass
__global__ void k_out2(const __half2* __restrict__ hh, const float* __restrict__ stats,
                       const float* __restrict__ gamma, const float* __restrict__ beta,
                       float2* __restrict__ out2, int n2, float invN) {
  int i = blockIdx.x * blockDim.x + threadIdx.x;
  if (i < n2) {
    int cb = (i & 31) * 2;
    float m0 = stats[cb] * invN, m1 = stats[cb + 1] * invN;
    float v0 = stats[64 + cb] * invN - m0 * m0;
    float v1 = stats[64 + cb + 1] * invN - m1 * m1;
    float sc0 = gamma[cb] * rsqrtf(v0 + 1e-5f);
    float sc1 = gamma[cb + 1] * rsqrtf(v1 + 1e-5f);
    float sh0 = beta[cb] - m0 * sc0;
    float sh1 = beta[cb + 1] - m1 * sc1;
    __half2 v = hh[i];
    float2 o;
    o.x = __half2float(v.x) * sc0 + sh0;
    o.y = __half2float(v.y) * sc1 + sh1;
    out2[i] = o;
  }
}

// ---------------- launch ----------------

extern "C" void kernel_launch(void* const* d_in, const int* in_sizes, int n_in,
                              void* d_out, int out_size, void* d_ws, size_t ws_size,
                              hipStream_t stream) {
  const float* x     = (const float*)d_in[0];
  const int*   ei    = (const int*)d_in[1];
  const float* We    = (const float*)d_in[2];
  const float* be    = (const float*)d_in[3];
  const float* Wn    = (const float*)d_in[4];
  const float* bnode = (const float*)d_in[5];
  const float* pa    = (const float*)d_in[6];
  const float* gamma = (const float*)d_in[7];
  const float* beta  = (const float*)d_in[8];

  int N = in_sizes[0] / 64;
  int E = in_sizes[1] / 2;
  const int* srcA = ei;
  const int* dstA = ei + E;

  int NBUCK = (N + NPB - 1) / NPB;     // 391

  char* ws = (char*)d_ws;
  size_t off = 0;
  auto alloc = [&](size_t bytes) -> void* {
    void* p = (void*)(ws + off);
    off += (bytes + 255) & ~(size_t)255;
    return p;
  };
  int*    cur    = (int*)alloc((size_t)NBUCK * 4);
  float*  stats  = (float*)alloc(128 * 4);
  int*    packed = (int*)alloc((size_t)NBUCK * CAPP * 4);
  int*    csr    = (int*)alloc((size_t)NBUCK * CAP8 * 4);
  int*    offA   = (int*)alloc((size_t)N * 4);
  int*    deg    = (int*)alloc((size_t)N * 4);
  __half* xh     = (__half*)alloc((size_t)(N + 1) * 64 * 2);  // +1 zero row for pads
  __half* Sh     = (__half*)alloc((size_t)N * 64 * 2);
  __half* Hh     = (__half*)alloc((size_t)N * 64 * 2);
  __half* Wfrag  = (__half*)alloc((size_t)24 * 512 * 2);
  float*  c2     = (float*)alloc(64 * 4);

  int FGRID = (E + FCHUNK - 1) / FCHUNK;   // 261
  int n4 = N * 16;
  int XGRID = (n4 + 255) / 256;            // 6250
  int n2 = N * 32;
  int ntile = N / 16;                       // 6250
  int mgrid = (ntile + 3) / 4;              // 1563 blocks -> 1 tile per wave

  k_prep<<<XGRID + 26, 256, 0, stream>>>(
      (const float4*)x, (__half2*)xh, n4, XGRID, We, be, Wn, Wfrag, c2,
      cur, stats, NBUCK, N);
  k_fill3<<<FGRID, 1024, 0, stream>>>(srcA, dstA, cur, packed, E);
  k_sort<<<NBUCK, 256, 0, stream>>>(packed, cur, csr, offA, deg, N);
  k_agg<<<2048, 256, 0, stream>>>((const f16x2*)xh, offA, deg, csr, (f16x2*)Sh, N);
  k_nodeM<<<mgrid, 256, 0, stream>>>(xh, Sh, deg, Wfrag, c2, bnode, pa, Hh, N);
  k_stats<<<256, 256, 0, stream>>>((const __half2*)Hh, stats, n2);
  k_out2<<<(n2 + 255) / 256, 256, 0, stream>>>((const __half2*)Hh, stats, gamma, beta,
                                               (float2*)d_out, n2, 1.0f / (float)N);
}

// Round 17
// 128.224 us; speedup vs baseline: 1.0149x; 1.0149x over previous
//
#include <hip/hip_runtime.h>
#include <hip/hip_fp16.h>

typedef _Float16 f16x8 __attribute__((ext_vector_type(8)));
typedef _Float16 f16x2 __attribute__((ext_vector_type(2)));
typedef float f32x4 __attribute__((ext_vector_type(4)));

#define NPB 256      // nodes per bucket (dst >> 8)
#define FCHUNK 6144  // edges per fill block (6 per thread @ 1024 threads)
#define MAXBK 512    // LDS bucket array size (>= NBUCK=391)
#define CAPP 5120    // static packed capacity per bucket (mean 4092, sigma 64)
#define CAP8 6144    // static padded-csr capacity per bucket

// fused prep: [0,XGRID) x fp32->fp16; [XGRID,+24) weight fragments;
// XGRID+24: c2 + zero row N; XGRID+25: cursor/stats init
__global__ __launch_bounds__(256) void k_prep(
    const float4* __restrict__ x4, __half2* __restrict__ xh2, int n4, int XGRID,
    const float* __restrict__ We, const float* __restrict__ be,
    const float* __restrict__ Wn, __half* __restrict__ Wfrag, float* __restrict__ c2,
    int* __restrict__ cur, float* __restrict__ stats, int nbuck, int N) {
  int b = blockIdx.x, t = threadIdx.x;
  if (b < XGRID) {
    int i = b * 256 + t;
    if (i < n4) {
      float4 v = x4[i];
      __half2 a, c;
      a.x = __float2half_rn(v.x); a.y = __float2half_rn(v.y);
      c.x = __float2half_rn(v.z); c.y = __float2half_rn(v.w);
      xh2[2 * i] = a;
      xh2[2 * i + 1] = c;
    }
  } else {
    int mb = b - XGRID;
    if (mb < 24) {
      int mat = mb >> 3, kk = (mb >> 2) & 1, ct = mb & 3;
      for (int tt = t; tt < 512; tt += 256) {
        int lane = tt >> 3, j = tt & 7;
        int k = kk * 32 + ((lane >> 4) & 3) * 8 + j;
        int col = ct * 16 + (lane & 15);
        float v;
        if (mat == 0) {
          v = Wn[k * 64 + col];
        } else if (mat == 1) {
          float a = 0.f;
          for (int m = 0; m < 64; ++m) a += We[k * 64 + m] * Wn[(64 + m) * 64 + col];
          v = a;
        } else {
          float a = 0.f;
          for (int m = 0; m < 64; ++m) a += We[(64 + k) * 64 + m] * Wn[(64 + m) * 64 + col];
          v = a;
        }
        Wfrag[mb * 512 + tt] = __float2half_rn(v);
      }
    } else if (mb == 24) {
      if (t < 64) {
        float a = 0.f;
        for (int m = 0; m < 64; ++m) a += be[m] * Wn[(64 + m) * 64 + t];
        c2[t] = a;
      } else if (t < 96) {
        __half2 z; z.x = __float2half_rn(0.f); z.y = __float2half_rn(0.f);
        xh2[(size_t)N * 32 + (t - 64)] = z;   // zero row N (pad target)
      }
    } else {
      for (int i = t; i < nbuck; i += 256) cur[i] = i * CAPP;
      if (t < 128) stats[t] = 0.f;
    }
  }
}

// scatter edges into static bucket segments; 1024 threads/block for occupancy
__global__ __launch_bounds__(1024) void k_fill3(const int* __restrict__ src,
    const int* __restrict__ dst, int* __restrict__ cur,
    int* __restrict__ packed, int E) {
  __shared__ int lh[MAXBK];
  __shared__ int gbase[MAXBK];
  int t = threadIdx.x;
  int e0 = blockIdx.x * FCHUNK;
  int e1 = min(e0 + FCHUNK, E);
  for (int i = t; i < MAXBK; i += 1024) lh[i] = 0;
  __syncthreads();
  int dv[6];
#pragma unroll
  for (int i = 0; i < 6; ++i) {
    int e = e0 + t + i * 1024;
    dv[i] = (e < e1) ? dst[e] : -1;
    if (dv[i] >= 0) atomicAdd(&lh[dv[i] >> 8], 1);
  }
  __syncthreads();
  for (int i = t; i < MAXBK; i += 1024) {
    int c = lh[i];
    gbase[i] = c ? atomicAdd(&cur[i], c) : 0;
    lh[i] = 0;  // reuse as local cursor
  }
  __syncthreads();
#pragma unroll
  for (int i = 0; i < 6; ++i) {
    int d = dv[i];
    if (d >= 0) {
      int e = e0 + t + i * 1024;
      int bk = d >> 8;
      int lp = atomicAdd(&lh[bk], 1);
      packed[gbase[bk] + lp] = src[e] | ((d & 255) << 20);
    }
  }
}

// per-bucket counting sort -> 8-PADDED per-node CSR; 1024 threads for occupancy
// (scan phase runs masked on first 256 threads with unconditional barriers)
__global__ __launch_bounds__(1024) void k_sort(const int* __restrict__ packed,
    const int* __restrict__ cur, int* __restrict__ csr,
    int* __restrict__ offA, int* __restrict__ deg, int N) {
  __shared__ int hist[NPB];
  __shared__ int sc[NPB];
  __shared__ int curs[NPB];
  int b = blockIdx.x, t = threadIdx.x;
  if (t < NPB) hist[t] = 0;
  __syncthreads();
  int e0 = b * CAPP;
  int e1 = cur[b];             // end of this bucket's real edges
  for (int e = e0 + t; e < e1; e += 1024)
    atomicAdd(&hist[(packed[e] >> 20) & 255], 1);
  __syncthreads();
  int v = (t < NPB) ? hist[t] : 0;
  int pv = (v + 7) & ~7;       // padded degree
  if (t < NPB) sc[t] = pv;
  __syncthreads();
  for (int d = 1; d < 256; d <<= 1) {
    int a = (t >= d && t < NPB) ? sc[t - d] : 0;
    __syncthreads();
    if (t < NPB) sc[t] += a;
    __syncthreads();
  }
  if (t < NPB) {
    int ex = b * CAP8 + sc[t] - pv;   // padded CSR start for this node
    curs[t] = ex;
    int n = b * NPB + t;
    if (n < N) { offA[n] = ex; deg[n] = v; }
    for (int k = v; k < pv; ++k) csr[ex + k] = N;  // pad slots (disjoint)
  }
  __syncthreads();
  for (int e = e0 + t; e < e1; e += 1024) {
    int pk = packed[e];
    int p = atomicAdd(&curs[(pk >> 20) & 255], 1);
    csr[p] = pk & 0xFFFFF;
  }
}

// S[n] = sum over incoming edges of x[src]. Tail-free padded CSR, pure 8-edge
// batches; scalar csr via readfirstlane; dword gather = 2 edges x 2 feats;
// DUAL-node interleave (round-15 best); shfl_xor(32) slot merge.
__global__ void k_agg(const f16x2* __restrict__ xh2, const int* __restrict__ offA,
                      const int* __restrict__ deg, const int* __restrict__ csr,
                      f16x2* __restrict__ Sh2, int N) {
  int t = threadIdx.x;
  unsigned lane = t & 63;
  unsigned f = lane & 31;          // feature-pair index
  int slot = (int)(lane >> 5);     // 0/1: which edge of a pair
  int wid = (blockIdx.x * blockDim.x + t) >> 6;
  int nw = (gridDim.x * blockDim.x) >> 6;
  for (int n = wid; n < N; n += 2 * nw) {
    int nB = n + nw;
    int j0A = offA[n];
    int pdA = (deg[n] + 7) & ~7;
    int j0B = (nB < N) ? offA[nB] : 0;
    int pdB = (nB < N) ? ((deg[nB] + 7) & ~7) : 0;
    f16x2 aA0 = {0, 0}, aA1 = {0, 0}, aB0 = {0, 0}, aB1 = {0, 0};
    int jA = 0, jB = 0;
    for (; jA < pdA && jB < pdB; jA += 8, jB += 8) {
      int ua = __builtin_amdgcn_readfirstlane(j0A + jA);
      int ub = __builtin_amdgcn_readfirstlane(j0B + jB);
      int a0 = csr[ua + 0], a1 = csr[ua + 1], a2 = csr[ua + 2], a3 = csr[ua + 3];
      int a4 = csr[ua + 4], a5 = csr[ua + 5], a6 = csr[ua + 6], a7 = csr[ua + 7];
      int b0 = csr[ub + 0], b1 = csr[ub + 1], b2 = csr[ub + 2], b3 = csr[ub + 3];
      int b4 = csr[ub + 4], b5 = csr[ub + 5], b6 = csr[ub + 6], b7 = csr[ub + 7];
      unsigned sA0 = (unsigned)(slot ? a1 : a0), sA1 = (unsigned)(slot ? a3 : a2);
      unsigned sA2 = (unsigned)(slot ? a5 : a4), sA3 = (unsigned)(slot ? a7 : a6);
      unsigned sB0 = (unsigned)(slot ? b1 : b0), sB1 = (unsigned)(slot ? b3 : b2);
      unsigned sB2 = (unsigned)(slot ? b5 : b4), sB3 = (unsigned)(slot ? b7 : b6);
      f16x2 vA0 = xh2[(sA0 << 5) | f], vA1 = xh2[(sA1 << 5) | f];
      f16x2 vA2 = xh2[(sA2 << 5) | f], vA3 = xh2[(sA3 << 5) | f];
      f16x2 vB0 = xh2[(sB0 << 5) | f], vB1 = xh2[(sB1 << 5) | f];
      f16x2 vB2 = xh2[(sB2 << 5) | f], vB3 = xh2[(sB3 << 5) | f];
      aA0 += vA0; aA1 += vA1; aA0 += vA2; aA1 += vA3;
      aB0 += vB0; aB1 += vB1; aB0 += vB2; aB1 += vB3;
    }
    for (; jA < pdA; jA += 8) {
      int ua = __builtin_amdgcn_readfirstlane(j0A + jA);
      int a0 = csr[ua + 0], a1 = csr[ua + 1], a2 = csr[ua + 2], a3 = csr[ua + 3];
      int a4 = csr[ua + 4], a5 = csr[ua + 5], a6 = csr[ua + 6], a7 = csr[ua + 7];
      unsigned s0 = (unsigned)(slot ? a1 : a0), s1 = (unsigned)(slot ? a3 : a2);
      unsigned s2 = (unsigned)(slot ? a5 : a4), s3 = (unsigned)(slot ? a7 : a6);
      aA0 += xh2[(s0 << 5) | f]; aA1 += xh2[(s1 << 5) | f];
      aA0 += xh2[(s2 << 5) | f]; aA1 += xh2[(s3 << 5) | f];
    }
    for (; jB < pdB; jB += 8) {
      int ub = __builtin_amdgcn_readfirstlane(j0B + jB);
      int b0 = csr[ub + 0], b1 = csr[ub + 1], b2 = csr[ub + 2], b3 = csr[ub + 3];
      int b4 = csr[ub + 4], b5 = csr[ub + 5], b6 = csr[ub + 6], b7 = csr[ub + 7];
      unsigned s0 = (unsigned)(slot ? b1 : b0), s1 = (unsigned)(slot ? b3 : b2);
      unsigned s2 = (unsigned)(slot ? b5 : b4), s3 = (unsigned)(slot ? b7 : b6);
      aB0 += xh2[(s0 << 5) | f]; aB1 += xh2[(s1 << 5) | f];
      aB0 += xh2[(s2 << 5) | f]; aB1 += xh2[(s3 << 5) | f];
    }
    // slot merge + store
    f16x2 pa = aA0 + aA1;
    unsigned ua = __builtin_bit_cast(unsigned, pa);
    unsigned ux = (unsigned)__shfl_xor((int)ua, 32);
    f16x2 totA = pa + __builtin_bit_cast(f16x2, ux);
    if (slot == 0) Sh2[((unsigned)n << 5) | f] = totA;
    if (nB < N) {
      f16x2 pb = aB0 + aB1;
      unsigned vb = __builtin_bit_cast(unsigned, pb);
      unsigned vx = (unsigned)__shfl_xor((int)vb, 32);
      f16x2 totB = pb + __builtin_bit_cast(f16x2, vx);
      if (slot == 0) Sh2[((unsigned)nB << 5) | f] = totB;
    }
  }
}

// node model via MFMA + per-block stats partials (LDS reduce, non-atomic global write)
__global__ __launch_bounds__(256) void k_nodeM(const __half* __restrict__ xh,
    const __half* __restrict__ Sh, const int* __restrict__ deg,
    const __half* __restrict__ Wfrag, const float* __restrict__ c2,
    const float* __restrict__ bnode, const float* __restrict__ pa,
    __half* __restrict__ Hh, float* __restrict__ pstats, int N) {
  __shared__ float ls[128];
  const f16x8* WF = (const f16x8*)Wfrag;
  int t = threadIdx.x, lane = t & 63;
  if (t < 128) ls[t] = 0.f;
  f16x8 B[24];
#pragma unroll
  for (int f = 0; f < 24; ++f) B[f] = WF[f * 64 + lane];
  float slope = pa[0];
  int wid = (blockIdx.x * blockDim.x + t) >> 6;
  int nw = (gridDim.x * blockDim.x) >> 6;
  int ntile = N >> 4;
  int r = lane & 15, g = lane >> 4;
  float ws[4] = {0, 0, 0, 0}, wq[4] = {0, 0, 0, 0};
  __syncthreads();
  for (int tile = wid; tile < ntile; tile += nw) {
    int n0 = tile << 4;
    float dg[4];
#pragma unroll
    for (int q = 0; q < 4; ++q) dg[q] = (float)deg[n0 + g * 4 + q];
    const f16x8* xp = (const f16x8*)(xh + (size_t)(n0 + r) * 64 + g * 8);
    const f16x8* sp = (const f16x8*)(Sh + (size_t)(n0 + r) * 64 + g * 8);
    f16x8 ax0 = xp[0], ax1 = xp[4];
    f16x8 as0 = sp[0], as1 = sp[4];
    f32x4 accA[4], accB[4];
#pragma unroll
    for (int ct = 0; ct < 4; ++ct) {
      f32x4 a = {0.f, 0.f, 0.f, 0.f};
      a = __builtin_amdgcn_mfma_f32_16x16x32_f16(ax0, B[0 + ct], a, 0, 0, 0);
      a = __builtin_amdgcn_mfma_f32_16x16x32_f16(ax1, B[4 + ct], a, 0, 0, 0);
      a = __builtin_amdgcn_mfma_f32_16x16x32_f16(as0, B[8 + ct], a, 0, 0, 0);
      a = __builtin_amdgcn_mfma_f32_16x16x32_f16(as1, B[12 + ct], a, 0, 0, 0);
      accA[ct] = a;
      f32x4 bb = {0.f, 0.f, 0.f, 0.f};
      bb = __builtin_amdgcn_mfma_f32_16x16x32_f16(ax0, B[16 + ct], bb, 0, 0, 0);
      bb = __builtin_amdgcn_mfma_f32_16x16x32_f16(ax1, B[20 + ct], bb, 0, 0, 0);
      accB[ct] = bb;
    }
#pragma unroll
    for (int ct = 0; ct < 4; ++ct) {
      int c = ct * 16 + r;
      float cc = c2[c], bv = bnode[c];
#pragma unroll
      for (int q = 0; q < 4; ++q) {
        float hv = accA[ct][q] + dg[q] * (accB[ct][q] + cc) + bv;
        hv = hv >= 0.f ? hv : slope * hv;
        ws[ct] += hv; wq[ct] += hv * hv;
        Hh[(size_t)(n0 + g * 4 + q) * 64 + c] = __float2half_rn(hv);
      }
    }
  }
#pragma unroll
  for (int ct = 0; ct < 4; ++ct) {
    int c = ct * 16 + r;
    atomicAdd(&ls[c], ws[ct]);         // LDS atomics: cheap, block-local
    atomicAdd(&ls[64 + c], wq[ct]);
  }
  __syncthreads();
  if (t < 128) pstats[(size_t)blockIdx.x * 128 + t] = ls[t];
}

// reduce per-block partials (nb x 128) -> stats[128] (16K atomics total)
__global__ __launch_bounds__(256) void k_stats(const float* __restrict__ pstats,
    float* __restrict__ stats, int nb) {
  int t = threadIdx.x;
  int col = t & 127;
  int half = t >> 7;  // 0/1
  float acc = 0.f;
  for (int i = blockIdx.x * 2 + half; i < nb; i += gridDim.x * 2)
    acc += pstats[(size_t)i * 128 + col];
  atomicAdd(&stats[col], acc);
}

// BN finalize fused into the output pass
__global__ void k_out2(const __half2* __restrict__ hh, const float* __restrict__ stats,
                       const float* __restrict__ gamma, const float* __restrict__ beta,
                       float2* __restrict__ out2, int n2, float invN) {
  int i = blockIdx.x * blockDim.x + threadIdx.x;
  if (i < n2) {
    int cb = (i & 31) * 2;
    float m0 = stats[cb] * invN, m1 = stats[cb + 1] * invN;
    float v0 = stats[64 + cb] * invN - m0 * m0;
    float v1 = stats[64 + cb + 1] * invN - m1 * m1;
    float sc0 = gamma[cb] * rsqrtf(v0 + 1e-5f);
    float sc1 = gamma[cb + 1] * rsqrtf(v1 + 1e-5f);
    float sh0 = beta[cb] - m0 * sc0;
    float sh1 = beta[cb + 1] - m1 * sc1;
    __half2 v = hh[i];
    float2 o;
    o.x = __half2float(v.x) * sc0 + sh0;
    o.y = __half2float(v.y) * sc1 + sh1;
    out2[i] = o;
  }
}

// ---------------- launch ----------------

extern "C" void kernel_launch(void* const* d_in, const int* in_sizes, int n_in,
                              void* d_out, int out_size, void* d_ws, size_t ws_size,
                              hipStream_t stream) {
  const float* x     = (const float*)d_in[0];
  const int*   ei    = (const int*)d_in[1];
  const float* We    = (const float*)d_in[2];
  const float* be    = (const float*)d_in[3];
  const float* Wn    = (const float*)d_in[4];
  const float* bnode = (const float*)d_in[5];
  const float* pa    = (const float*)d_in[6];
  const float* gamma = (const float*)d_in[7];
  const float* beta  = (const float*)d_in[8];

  int N = in_sizes[0] / 64;
  int E = in_sizes[1] / 2;
  const int* srcA = ei;
  const int* dstA = ei + E;

  int NBUCK = (N + NPB - 1) / NPB;     // 391

  char* ws = (char*)d_ws;
  size_t off = 0;
  auto alloc = [&](size_t bytes) -> void* {
    void* p = (void*)(ws + off);
    off += (bytes + 255) & ~(size_t)255;
    return p;
  };
  int ntile = N / 16;                       // 6250
  int mgrid = (ntile + 3) / 4;              // 1563 blocks -> 1 tile per wave

  int*    cur    = (int*)alloc((size_t)NBUCK * 4);
  float*  stats  = (float*)alloc(128 * 4);
  int*    packed = (int*)alloc((size_t)NBUCK * CAPP * 4);
  int*    csr    = (int*)alloc((size_t)NBUCK * CAP8 * 4);
  int*    offA   = (int*)alloc((size_t)N * 4);
  int*    deg    = (int*)alloc((size_t)N * 4);
  __half* xh     = (__half*)alloc((size_t)(N + 1) * 64 * 2);  // +1 zero row for pads
  __half* Sh     = (__half*)alloc((size_t)N * 64 * 2);
  __half* Hh     = (__half*)alloc((size_t)N * 64 * 2);
  __half* Wfrag  = (__half*)alloc((size_t)24 * 512 * 2);
  float*  c2     = (float*)alloc(64 * 4);
  float*  pstats = (float*)alloc((size_t)mgrid * 128 * 4);

  int FGRID = (E + FCHUNK - 1) / FCHUNK;   // 261
  int n4 = N * 16;
  int XGRID = (n4 + 255) / 256;            // 6250
  int n2 = N * 32;

  k_prep<<<XGRID + 26, 256, 0, stream>>>(
      (const float4*)x, (__half2*)xh, n4, XGRID, We, be, Wn, Wfrag, c2,
      cur, stats, NBUCK, N);
  k_fill3<<<FGRID, 1024, 0, stream>>>(srcA, dstA, cur, packed, E);
  k_sort<<<NBUCK, 1024, 0, stream>>>(packed, cur, csr, offA, deg, N);
  k_agg<<<2048, 256, 0, stream>>>((const f16x2*)xh, offA, deg, csr, (f16x2*)Sh, N);
  k_nodeM<<<mgrid, 256, 0, stream>>>(xh, Sh, deg, Wfrag, c2, bnode, pa, Hh, pstats, N);
  k_stats<<<64, 256, 0, stream>>>(pstats, stats, mgrid);
  k_out2<<<(n2 + 255) / 256, 256, 0, stream>>>((const __half2*)Hh, stats, gamma, beta,
                                               (float2*)d_out, n2, 1.0f / (float)N);
}

// Round 18
// 121.376 us; speedup vs baseline: 1.0721x; 1.0564x over previous
//
#include <hip/hip_runtime.h>
#include <hip/hip_fp16.h>

typedef _Float16 f16x8 __attribute__((ext_vector_type(8)));
typedef _Float16 f16x2 __attribute__((ext_vector_type(2)));
typedef float f32x4 __attribute__((ext_vector_type(4)));

#define NPB 256      // nodes per bucket (dst >> 8)
#define FCHUNK 6144  // edges per fill block (6 per thread @ 1024 threads)
#define MAXBK 512    // LDS bucket array size (>= NBUCK=391)
#define SEGCAP 64    // slots per (fill-block, bucket) segment (mean 15.7, +8sigma<64)
#define CAP8 6144    // static padded-csr capacity per bucket

// FUSED prep + fill. 1024-thread blocks, roles by blockIdx:
//  [0,X2): x fp32->fp16 | [X2,X2+24): weight frags | X2+24: c2+zero-row+stats
//  [X2+25, +FGRID): edge fill into static [bucket][fblk][SEGCAP] segments
//  (fill needs NO initialized state: counts written non-atomically per block)
__global__ __launch_bounds__(1024) void k_prepfill(
    const float4* __restrict__ x4, __half2* __restrict__ xh2, int n4, int X2,
    const int* __restrict__ src, const int* __restrict__ dst,
    int* __restrict__ cnt, int* __restrict__ packed2, int E, int FGRID,
    const float* __restrict__ We, const float* __restrict__ be,
    const float* __restrict__ Wn, __half* __restrict__ Wfrag, float* __restrict__ c2,
    float* __restrict__ stats, int nbuck, int N) {
  int b = blockIdx.x, t = threadIdx.x;
  if (b < X2) {
    int i = b * 1024 + t;
    if (i < n4) {
      float4 v = x4[i];
      __half2 a, c;
      a.x = __float2half_rn(v.x); a.y = __float2half_rn(v.y);
      c.x = __float2half_rn(v.z); c.y = __float2half_rn(v.w);
      xh2[2 * i] = a;
      xh2[2 * i + 1] = c;
    }
  } else if (b < X2 + 24) {
    int mb = b - X2;
    if (t < 512) {
      int mat = mb >> 3, kk = (mb >> 2) & 1, ct = mb & 3;
      int lane = t >> 3, j = t & 7;
      int k = kk * 32 + ((lane >> 4) & 3) * 8 + j;
      int col = ct * 16 + (lane & 15);
      float v;
      if (mat == 0) {
        v = Wn[k * 64 + col];
      } else if (mat == 1) {
        float a = 0.f;
        for (int m = 0; m < 64; ++m) a += We[k * 64 + m] * Wn[(64 + m) * 64 + col];
        v = a;
      } else {
        float a = 0.f;
        for (int m = 0; m < 64; ++m) a += We[(64 + k) * 64 + m] * Wn[(64 + m) * 64 + col];
        v = a;
      }
      Wfrag[mb * 512 + t] = __float2half_rn(v);
    }
  } else if (b == X2 + 24) {
    if (t < 64) {
      float a = 0.f;
      for (int m = 0; m < 64; ++m) a += be[m] * Wn[(64 + m) * 64 + t];
      c2[t] = a;
    } else if (t < 96) {
      __half2 z; z.x = __float2half_rn(0.f); z.y = __float2half_rn(0.f);
      xh2[(size_t)N * 32 + (t - 64)] = z;   // zero row N (pad target)
    } else if (t >= 128 && t < 256) {
      stats[t - 128] = 0.f;
    }
  } else {
    int fb = b - (X2 + 25);
    __shared__ int lh[MAXBK];
    int e0 = fb * FCHUNK;
    int e1 = min(e0 + FCHUNK, E);
    for (int i = t; i < MAXBK; i += 1024) lh[i] = 0;
    __syncthreads();
    int dv[6];
#pragma unroll
    for (int i = 0; i < 6; ++i) {
      int e = e0 + t + i * 1024;
      dv[i] = (e < e1) ? dst[e] : -1;
      if (dv[i] >= 0) atomicAdd(&lh[dv[i] >> 8], 1);
    }
    __syncthreads();
    for (int i = t; i < MAXBK; i += 1024) {
      if (i < nbuck) cnt[(size_t)i * FGRID + fb] = lh[i];  // non-atomic count
      lh[i] = 0;  // reuse as local cursor
    }
    __syncthreads();
#pragma unroll
    for (int i = 0; i < 6; ++i) {
      int d = dv[i];
      if (d >= 0) {
        int e = e0 + t + i * 1024;
        int bk = d >> 8;
        unsigned lp = (unsigned)atomicAdd(&lh[bk], 1);
        if (lp < SEGCAP)
          packed2[((size_t)bk * FGRID + fb) * SEGCAP + lp] = src[e] | ((d & 255) << 20);
      }
    }
  }
}

// per-bucket counting sort over segmented input -> 8-PADDED per-node CSR
__global__ __launch_bounds__(1024) void k_sort(const int* __restrict__ packed2,
    const int* __restrict__ cnt, int* __restrict__ csr,
    int* __restrict__ offA, int* __restrict__ deg, int FGRID, int N) {
  __shared__ int scnt[288];
  __shared__ int hist[NPB];
  __shared__ int sc[NPB];
  __shared__ int curs[NPB];
  int b = blockIdx.x, t = threadIdx.x;
  if (t < NPB) hist[t] = 0;
  for (int i = t; i < FGRID; i += 1024) scnt[i] = cnt[(size_t)b * FGRID + i];
  __syncthreads();
  int slots = FGRID * SEGCAP;
  const int* seg = packed2 + (size_t)b * FGRID * SEGCAP;
  for (int idx = t; idx < slots; idx += 1024) {
    int s = idx >> 6, k = idx & 63;
    if (k < scnt[s]) atomicAdd(&hist[(seg[idx] >> 20) & 255], 1);
  }
  __syncthreads();
  int v = (t < NPB) ? hist[t] : 0;
  int pv = (v + 7) & ~7;       // padded degree
  if (t < NPB) sc[t] = pv;
  __syncthreads();
  for (int d = 1; d < 256; d <<= 1) {
    int a = (t >= d && t < NPB) ? sc[t - d] : 0;
    __syncthreads();
    if (t < NPB) sc[t] += a;
    __syncthreads();
  }
  if (t < NPB) {
    int ex = b * CAP8 + sc[t] - pv;   // padded CSR start for this node
    curs[t] = ex;
    int n = b * NPB + t;
    if (n < N) { offA[n] = ex; deg[n] = v; }
    for (int k = v; k < pv; ++k) csr[ex + k] = N;  // pad slots (disjoint)
  }
  __syncthreads();
  for (int idx = t; idx < slots; idx += 1024) {
    int s = idx >> 6, k = idx & 63;
    if (k < scnt[s]) {
      int pk = seg[idx];
      int p = atomicAdd(&curs[(pk >> 20) & 255], 1);
      csr[p] = pk & 0xFFFFF;
    }
  }
}

// S[n] = sum over incoming edges of x[src]. Tail-free padded CSR, pure 8-edge
// batches; scalar csr via readfirstlane; dword gather = 2 edges x 2 feats;
// DUAL-node interleave (round-15 best); shfl_xor(32) slot merge.
__global__ void k_agg(const f16x2* __restrict__ xh2, const int* __restrict__ offA,
                      const int* __restrict__ deg, const int* __restrict__ csr,
                      f16x2* __restrict__ Sh2, int N) {
  int t = threadIdx.x;
  unsigned lane = t & 63;
  unsigned f = lane & 31;          // feature-pair index
  int slot = (int)(lane >> 5);     // 0/1: which edge of a pair
  int wid = (blockIdx.x * blockDim.x + t) >> 6;
  int nw = (gridDim.x * blockDim.x) >> 6;
  for (int n = wid; n < N; n += 2 * nw) {
    int nB = n + nw;
    int j0A = offA[n];
    int pdA = (deg[n] + 7) & ~7;
    int j0B = (nB < N) ? offA[nB] : 0;
    int pdB = (nB < N) ? ((deg[nB] + 7) & ~7) : 0;
    f16x2 aA0 = {0, 0}, aA1 = {0, 0}, aB0 = {0, 0}, aB1 = {0, 0};
    int jA = 0, jB = 0;
    for (; jA < pdA && jB < pdB; jA += 8, jB += 8) {
      int ua = __builtin_amdgcn_readfirstlane(j0A + jA);
      int ub = __builtin_amdgcn_readfirstlane(j0B + jB);
      int a0 = csr[ua + 0], a1 = csr[ua + 1], a2 = csr[ua + 2], a3 = csr[ua + 3];
      int a4 = csr[ua + 4], a5 = csr[ua + 5], a6 = csr[ua + 6], a7 = csr[ua + 7];
      int b0 = csr[ub + 0], b1 = csr[ub + 1], b2 = csr[ub + 2], b3 = csr[ub + 3];
      int b4 = csr[ub + 4], b5 = csr[ub + 5], b6 = csr[ub + 6], b7 = csr[ub + 7];
      unsigned sA0 = (unsigned)(slot ? a1 : a0), sA1 = (unsigned)(slot ? a3 : a2);
      unsigned sA2 = (unsigned)(slot ? a5 : a4), sA3 = (unsigned)(slot ? a7 : a6);
      unsigned sB0 = (unsigned)(slot ? b1 : b0), sB1 = (unsigned)(slot ? b3 : b2);
      unsigned sB2 = (unsigned)(slot ? b5 : b4), sB3 = (unsigned)(slot ? b7 : b6);
      f16x2 vA0 = xh2[(sA0 << 5) | f], vA1 = xh2[(sA1 << 5) | f];
      f16x2 vA2 = xh2[(sA2 << 5) | f], vA3 = xh2[(sA3 << 5) | f];
      f16x2 vB0 = xh2[(sB0 << 5) | f], vB1 = xh2[(sB1 << 5) | f];
      f16x2 vB2 = xh2[(sB2 << 5) | f], vB3 = xh2[(sB3 << 5) | f];
      aA0 += vA0; aA1 += vA1; aA0 += vA2; aA1 += vA3;
      aB0 += vB0; aB1 += vB1; aB0 += vB2; aB1 += vB3;
    }
    for (; jA < pdA; jA += 8) {
      int ua = __builtin_amdgcn_readfirstlane(j0A + jA);
      int a0 = csr[ua + 0], a1 = csr[ua + 1], a2 = csr[ua + 2], a3 = csr[ua + 3];
      int a4 = csr[ua + 4], a5 = csr[ua + 5], a6 = csr[ua + 6], a7 = csr[ua + 7];
      unsigned s0 = (unsigned)(slot ? a1 : a0), s1 = (unsigned)(slot ? a3 : a2);
      unsigned s2 = (unsigned)(slot ? a5 : a4), s3 = (unsigned)(slot ? a7 : a6);
      aA0 += xh2[(s0 << 5) | f]; aA1 += xh2[(s1 << 5) | f];
      aA0 += xh2[(s2 << 5) | f]; aA1 += xh2[(s3 << 5) | f];
    }
    for (; jB < pdB; jB += 8) {
      int ub = __builtin_amdgcn_readfirstlane(j0B + jB);
      int b0 = csr[ub + 0], b1 = csr[ub + 1], b2 = csr[ub + 2], b3 = csr[ub + 3];
      int b4 = csr[ub + 4], b5 = csr[ub + 5], b6 = csr[ub + 6], b7 = csr[ub + 7];
      unsigned s0 = (unsigned)(slot ? b1 : b0), s1 = (unsigned)(slot ? b3 : b2);
      unsigned s2 = (unsigned)(slot ? b5 : b4), s3 = (unsigned)(slot ? b7 : b6);
      aB0 += xh2[(s0 << 5) | f]; aB1 += xh2[(s1 << 5) | f];
      aB0 += xh2[(s2 << 5) | f]; aB1 += xh2[(s3 << 5) | f];
    }
    // slot merge + store
    f16x2 pa = aA0 + aA1;
    unsigned ua = __builtin_bit_cast(unsigned, pa);
    unsigned ux = (unsigned)__shfl_xor((int)ua, 32);
    f16x2 totA = pa + __builtin_bit_cast(f16x2, ux);
    if (slot == 0) Sh2[((unsigned)n << 5) | f] = totA;
    if (nB < N) {
      f16x2 pb = aB0 + aB1;
      unsigned vb = __builtin_bit_cast(unsigned, pb);
      unsigned vx = (unsigned)__shfl_xor((int)vb, 32);
      f16x2 totB = pb + __builtin_bit_cast(f16x2, vx);
      if (slot == 0) Sh2[((unsigned)nB << 5) | f] = totB;
    }
  }
}

// node model via MFMA + per-block stats partials (LDS reduce, non-atomic global write)
__global__ __launch_bounds__(256) void k_nodeM(const __half* __restrict__ xh,
    const __half* __restrict__ Sh, const int* __restrict__ deg,
    const __half* __restrict__ Wfrag, const float* __restrict__ c2,
    const float* __restrict__ bnode, const float* __restrict__ pa,
    __half* __restrict__ Hh, float* __restrict__ pstats, int N) {
  __shared__ float ls[128];
  const f16x8* WF = (const f16x8*)Wfrag;
  int t = threadIdx.x, lane = t & 63;
  if (t < 128) ls[t] = 0.f;
  f16x8 B[24];
#pragma unroll
  for (int f = 0; f < 24; ++f) B[f] = WF[f * 64 + lane];
  float slope = pa[0];
  int wid = (blockIdx.x * blockDim.x + t) >> 6;
  int nw = (gridDim.x * blockDim.x) >> 6;
  int ntile = N >> 4;
  int r = lane & 15, g = lane >> 4;
  float ws[4] = {0, 0, 0, 0}, wq[4] = {0, 0, 0, 0};
  __syncthreads();
  for (int tile = wid; tile < ntile; tile += nw) {
    int n0 = tile << 4;
    float dg[4];
#pragma unroll
    for (int q = 0; q < 4; ++q) dg[q] = (float)deg[n0 + g * 4 + q];
    const f16x8* xp = (const f16x8*)(xh + (size_t)(n0 + r) * 64 + g * 8);
    const f16x8* sp = (const f16x8*)(Sh + (size_t)(n0 + r) * 64 + g * 8);
    f16x8 ax0 = xp[0], ax1 = xp[4];
    f16x8 as0 = sp[0], as1 = sp[4];
    f32x4 accA[4], accB[4];
#pragma unroll
    for (int ct = 0; ct < 4; ++ct) {
      f32x4 a = {0.f, 0.f, 0.f, 0.f};
      a = __builtin_amdgcn_mfma_f32_16x16x32_f16(ax0, B[0 + ct], a, 0, 0, 0);
      a = __builtin_amdgcn_mfma_f32_16x16x32_f16(ax1, B[4 + ct], a, 0, 0, 0);
      a = __builtin_amdgcn_mfma_f32_16x16x32_f16(as0, B[8 + ct], a, 0, 0, 0);
      a = __builtin_amdgcn_mfma_f32_16x16x32_f16(as1, B[12 + ct], a, 0, 0, 0);
      accA[ct] = a;
      f32x4 bb = {0.f, 0.f, 0.f, 0.f};
      bb = __builtin_amdgcn_mfma_f32_16x16x32_f16(ax0, B[16 + ct], bb, 0, 0, 0);
      bb = __builtin_amdgcn_mfma_f32_16x16x32_f16(ax1, B[20 + ct], bb, 0, 0, 0);
      accB[ct] = bb;
    }
#pragma unroll
    for (int ct = 0; ct < 4; ++ct) {
      int c = ct * 16 + r;
      float cc = c2[c], bv = bnode[c];
#pragma unroll
      for (int q = 0; q < 4; ++q) {
        float hv = accA[ct][q] + dg[q] * (accB[ct][q] + cc) + bv;
        hv = hv >= 0.f ? hv : slope * hv;
        ws[ct] += hv; wq[ct] += hv * hv;
        Hh[(size_t)(n0 + g * 4 + q) * 64 + c] = __float2half_rn(hv);
      }
    }
  }
#pragma unroll
  for (int ct = 0; ct < 4; ++ct) {
    int c = ct * 16 + r;
    atomicAdd(&ls[c], ws[ct]);         // LDS atomics: block-local, cheap
    atomicAdd(&ls[64 + c], wq[ct]);
  }
  __syncthreads();
  if (t < 128) pstats[(size_t)blockIdx.x * 128 + t] = ls[t];
}

// reduce per-block partials (nb x 128) -> stats[128]
__global__ __launch_bounds__(256) void k_stats(const float* __restrict__ pstats,
    float* __restrict__ stats, int nb) {
  int t = threadIdx.x;
  int col = t & 127;
  int half = t >> 7;  // 0/1
  float acc = 0.f;
  for (int i = blockIdx.x * 2 + half; i < nb; i += gridDim.x * 2)
    acc += pstats[(size_t)i * 128 + col];
  atomicAdd(&stats[col], acc);
}

// BN finalize fused into the output pass
__global__ void k_out2(const __half2* __restrict__ hh, const float* __restrict__ stats,
                       const float* __restrict__ gamma, const float* __restrict__ beta,
                       float2* __restrict__ out2, int n2, float invN) {
  int i = blockIdx.x * blockDim.x + threadIdx.x;
  if (i < n2) {
    int cb = (i & 31) * 2;
    float m0 = stats[cb] * invN, m1 = stats[cb + 1] * invN;
    float v0 = stats[64 + cb] * invN - m0 * m0;
    float v1 = stats[64 + cb + 1] * invN - m1 * m1;
    float sc0 = gamma[cb] * rsqrtf(v0 + 1e-5f);
    float sc1 = gamma[cb + 1] * rsqrtf(v1 + 1e-5f);
    float sh0 = beta[cb] - m0 * sc0;
    float sh1 = beta[cb + 1] - m1 * sc1;
    __half2 v = hh[i];
    float2 o;
    o.x = __half2float(v.x) * sc0 + sh0;
    o.y = __half2float(v.y) * sc1 + sh1;
    out2[i] = o;
  }
}

// ---------------- launch ----------------

extern "C" void kernel_launch(void* const* d_in, const int* in_sizes, int n_in,
                              void* d_out, int out_size, void* d_ws, size_t ws_size,
                              hipStream_t stream) {
  const float* x     = (const float*)d_in[0];
  const int*   ei    = (const int*)d_in[1];
  const float* We    = (const float*)d_in[2];
  const float* be    = (const float*)d_in[3];
  const float* Wn    = (const float*)d_in[4];
  const float* bnode = (const float*)d_in[5];
  const float* pa    = (const float*)d_in[6];
  const float* gamma = (const float*)d_in[7];
  const float* beta  = (const float*)d_in[8];

  int N = in_sizes[0] / 64;
  int E = in_sizes[1] / 2;
  const int* srcA = ei;
  const int* dstA = ei + E;

  int NBUCK = (N + NPB - 1) / NPB;         // 391
  int FGRID = (E + FCHUNK - 1) / FCHUNK;   // 261

  char* ws = (char*)d_ws;
  size_t off = 0;
  auto alloc = [&](size_t bytes) -> void* {
    void* p = (void*)(ws + off);
    off += (bytes + 255) & ~(size_t)255;
    return p;
  };
  int ntile = N / 16;                       // 6250
  int mgrid = (ntile + 3) / 4;              // 1563 blocks -> 1 tile per wave

  float*  stats   = (float*)alloc(128 * 4);
  int*    cnt     = (int*)alloc((size_t)NBUCK * FGRID * 4);
  int*    packed2 = (int*)alloc((size_t)NBUCK * FGRID * SEGCAP * 4);  // 26 MB
  int*    csr     = (int*)alloc((size_t)NBUCK * CAP8 * 4);
  int*    offA    = (int*)alloc((size_t)N * 4);
  int*    deg     = (int*)alloc((size_t)N * 4);
  __half* xh      = (__half*)alloc((size_t)(N + 1) * 64 * 2);  // +1 zero row for pads
  __half* Sh      = (__half*)alloc((size_t)N * 64 * 2);
  __half* Hh      = (__half*)alloc((size_t)N * 64 * 2);
  __half* Wfrag   = (__half*)alloc((size_t)24 * 512 * 2);
  float*  c2      = (float*)alloc(64 * 4);
  float*  pstats  = (float*)alloc((size_t)mgrid * 128 * 4);

  int n4 = N * 16;
  int X2 = (n4 + 1023) / 1024;             // 1563
  int n2 = N * 32;
  int pgrid = X2 + 25 + FGRID;             // 1849

  k_prepfill<<<pgrid, 1024, 0, stream>>>(
      (const float4*)x, (__half2*)xh, n4, X2,
      srcA, dstA, cnt, packed2, E, FGRID,
      We, be, Wn, Wfrag, c2, stats, NBUCK, N);
  k_sort<<<NBUCK, 1024, 0, stream>>>(packed2, cnt, csr, offA, deg, FGRID, N);
  k_agg<<<2048, 256, 0, stream>>>((const f16x2*)xh, offA, deg, csr, (f16x2*)Sh, N);
  k_nodeM<<<mgrid, 256, 0, stream>>>(xh, Sh, deg, Wfrag, c2, bnode, pa, Hh, pstats, N);
  k_stats<<<64, 256, 0, stream>>>(pstats, stats, mgrid);
  k_out2<<<(n2 + 255) / 256, 256, 0, stream>>>((const __half2*)Hh, stats, gamma, beta,
                                               (float2*)d_out, n2, 1.0f / (float)N);
}

// Round 19
// 119.266 us; speedup vs baseline: 1.0911x; 1.0177x over previous
//
#include <hip/hip_runtime.h>
#include <hip/hip_fp16.h>

typedef _Float16 f16x8 __attribute__((ext_vector_type(8)));
typedef _Float16 f16x4 __attribute__((ext_vector_type(4)));
typedef float f32x4 __attribute__((ext_vector_type(4)));
typedef float f32x2 __attribute__((ext_vector_type(2)));

#define NPB 256      // nodes per bucket (dst >> 8)
#define FCHUNK 6144  // edges per fill block (6 per thread @ 1024 threads)
#define MAXBK 512    // LDS bucket array size (>= NBUCK=391)
#define SEGCAP 64    // slots per (fill-block, bucket) segment (mean 15.7, +8sigma<64)
#define CAP8 6144    // static padded-csr capacity per bucket

// FUSED prep + fill. 1024-thread blocks, roles by blockIdx:
//  [0,X2): x fp32->{fp16, fp8} | [X2,X2+24): weight frags | X2+24: c2+zero-rows+stats
//  [X2+25, +FGRID): edge fill into static [bucket][fblk][SEGCAP] segments
__global__ __launch_bounds__(1024) void k_prepfill(
    const float4* __restrict__ x4, __half2* __restrict__ xh2,
    unsigned* __restrict__ xq, int n4, int X2,
    const int* __restrict__ src, const int* __restrict__ dst,
    int* __restrict__ cnt, int* __restrict__ packed2, int E, int FGRID,
    const float* __restrict__ We, const float* __restrict__ be,
    const float* __restrict__ Wn, __half* __restrict__ Wfrag, float* __restrict__ c2,
    float* __restrict__ stats, int nbuck, int N) {
  int b = blockIdx.x, t = threadIdx.x;
  if (b < X2) {
    int i = b * 1024 + t;
    if (i < n4) {
      float4 v = x4[i];
      __half2 a, c;
      a.x = __float2half_rn(v.x); a.y = __float2half_rn(v.y);
      c.x = __float2half_rn(v.z); c.y = __float2half_rn(v.w);
      xh2[2 * i] = a;
      xh2[2 * i + 1] = c;
      int w = __builtin_amdgcn_cvt_pk_fp8_f32(v.x, v.y, 0, false);
      w = __builtin_amdgcn_cvt_pk_fp8_f32(v.z, v.w, w, true);
      xq[i] = (unsigned)w;
    }
  } else if (b < X2 + 24) {
    int mb = b - X2;
    if (t < 512) {
      int mat = mb >> 3, kk = (mb >> 2) & 1, ct = mb & 3;
      int lane = t >> 3, j = t & 7;
      int k = kk * 32 + ((lane >> 4) & 3) * 8 + j;
      int col = ct * 16 + (lane & 15);
      float v;
      if (mat == 0) {
        v = Wn[k * 64 + col];
      } else if (mat == 1) {
        float a = 0.f;
        for (int m = 0; m < 64; ++m) a += We[k * 64 + m] * Wn[(64 + m) * 64 + col];
        v = a;
      } else {
        float a = 0.f;
        for (int m = 0; m < 64; ++m) a += We[(64 + k) * 64 + m] * Wn[(64 + m) * 64 + col];
        v = a;
      }
      Wfrag[mb * 512 + t] = __float2half_rn(v);
    }
  } else if (b == X2 + 24) {
    if (t < 64) {
      float a = 0.f;
      for (int m = 0; m < 64; ++m) a += be[m] * Wn[(64 + m) * 64 + t];
      c2[t] = a;
    } else if (t < 96) {
      __half2 z; z.x = __float2half_rn(0.f); z.y = __float2half_rn(0.f);
      xh2[(size_t)N * 32 + (t - 64)] = z;   // zero fp16 row N (pad target)
    } else if (t < 112) {
      xq[(size_t)N * 16 + (t - 96)] = 0u;   // zero fp8 row N
    } else if (t >= 128 && t < 256) {
      stats[t - 128] = 0.f;
    }
  } else {
    int fb = b - (X2 + 25);
    __shared__ int lh[MAXBK];
    int e0 = fb * FCHUNK;
    int e1 = min(e0 + FCHUNK, E);
    for (int i = t; i < MAXBK; i += 1024) lh[i] = 0;
    __syncthreads();
    int dv[6];
#pragma unroll
    for (int i = 0; i < 6; ++i) {
      int e = e0 + t + i * 1024;
      dv[i] = (e < e1) ? dst[e] : -1;
      if (dv[i] >= 0) atomicAdd(&lh[dv[i] >> 8], 1);
    }
    __syncthreads();
    for (int i = t; i < MAXBK; i += 1024) {
      if (i < nbuck) cnt[(size_t)i * FGRID + fb] = lh[i];  // non-atomic count
      lh[i] = 0;  // reuse as local cursor
    }
    __syncthreads();
#pragma unroll
    for (int i = 0; i < 6; ++i) {
      int d = dv[i];
      if (d >= 0) {
        int e = e0 + t + i * 1024;
        int bk = d >> 8;
        unsigned lp = (unsigned)atomicAdd(&lh[bk], 1);
        if (lp < SEGCAP)
          packed2[((size_t)bk * FGRID + fb) * SEGCAP + lp] = src[e] | ((d & 255) << 20);
      }
    }
  }
}

// per-bucket counting sort over segmented input -> 8-PADDED per-node CSR
__global__ __launch_bounds__(1024) void k_sort(const int* __restrict__ packed2,
    const int* __restrict__ cnt, int* __restrict__ csr,
    int* __restrict__ offA, int* __restrict__ deg, int FGRID, int N) {
  __shared__ int scnt[288];
  __shared__ int hist[NPB];
  __shared__ int sc[NPB];
  __shared__ int curs[NPB];
  int b = blockIdx.x, t = threadIdx.x;
  if (t < NPB) hist[t] = 0;
  for (int i = t; i < FGRID; i += 1024) scnt[i] = cnt[(size_t)b * FGRID + i];
  __syncthreads();
  int slots = FGRID * SEGCAP;
  const int* seg = packed2 + (size_t)b * FGRID * SEGCAP;
  for (int idx = t; idx < slots; idx += 1024) {
    int s = idx >> 6, k = idx & 63;
    if (k < scnt[s]) atomicAdd(&hist[(seg[idx] >> 20) & 255], 1);
  }
  __syncthreads();
  int v = (t < NPB) ? hist[t] : 0;
  int pv = (v + 7) & ~7;       // padded degree
  if (t < NPB) sc[t] = pv;
  __syncthreads();
  for (int d = 1; d < 256; d <<= 1) {
    int a = (t >= d && t < NPB) ? sc[t - d] : 0;
    __syncthreads();
    if (t < NPB) sc[t] += a;
    __syncthreads();
  }
  if (t < NPB) {
    int ex = b * CAP8 + sc[t] - pv;   // padded CSR start for this node
    curs[t] = ex;
    int n = b * NPB + t;
    if (n < N) { offA[n] = ex; deg[n] = v; }
    for (int k = v; k < pv; ++k) csr[ex + k] = N;  // pad slots (disjoint)
  }
  __syncthreads();
  for (int idx = t; idx < slots; idx += 1024) {
    int s = idx >> 6, k = idx & 63;
    if (k < scnt[s]) {
      int pk = seg[idx];
      int p = atomicAdd(&curs[(pk >> 20) & 255], 1);
      csr[p] = pk & 0xFFFFF;
    }
  }
}

// one 8-edge batch for one node: 8 scalar csr reads, slot-select 2 edges,
// 2 dword fp8 gathers (4 feats each), HW cvt to f32, f32 accumulate.
#define FBATCH8(J0, J, AL, AH)                                                 \
  {                                                                            \
    int u_ = __builtin_amdgcn_readfirstlane((J0) + (J));                       \
    int e0_ = csr[u_ + 0], e1_ = csr[u_ + 1], e2_ = csr[u_ + 2], e3_ = csr[u_ + 3]; \
    int e4_ = csr[u_ + 4], e5_ = csr[u_ + 5], e6_ = csr[u_ + 6], e7_ = csr[u_ + 7]; \
    int p1_ = (slot & 1) ? e1_ : e0_, q1_ = (slot & 1) ? e3_ : e2_;            \
    int s1_ = (slot & 2) ? q1_ : p1_;                                          \
    int p2_ = (slot & 1) ? e5_ : e4_, q2_ = (slot & 1) ? e7_ : e6_;            \
    int s2_ = (slot & 2) ? q2_ : p2_;                                          \
    unsigned w1_ = xq[((unsigned)s1_ << 4) | q];                               \
    unsigned w2_ = xq[((unsigned)s2_ << 4) | q];                               \
    f32x2 l1_ = __builtin_amdgcn_cvt_pk_f32_fp8(w1_, false);                   \
    f32x2 h1_ = __builtin_amdgcn_cvt_pk_f32_fp8(w1_, true);                    \
    f32x2 l2_ = __builtin_amdgcn_cvt_pk_f32_fp8(w2_, false);                   \
    f32x2 h2_ = __builtin_amdgcn_cvt_pk_f32_fp8(w2_, true);                    \
    AL += l1_; AH += h1_; AL += l2_; AH += h2_;                                \
  }

// S[n] = sum over incoming edges of x[src]. fp8 table (64B/row), 4 edges per
// wave-load, f32 accumulate, 2-stage shfl_xor slot merge, fp16 S out.
__global__ void k_agg(const unsigned* __restrict__ xq, const int* __restrict__ offA,
                      const int* __restrict__ deg, const int* __restrict__ csr,
                      __half* __restrict__ Sh, int N) {
  int t = threadIdx.x;
  unsigned lane = t & 63;
  unsigned q = lane & 15;          // feature quad: features 4q..4q+3
  int slot = (int)(lane >> 4);     // 0..3: which edge of a group of 4
  int wid = (blockIdx.x * blockDim.x + t) >> 6;
  int nw = (gridDim.x * blockDim.x) >> 6;
  for (int n = wid; n < N; n += 2 * nw) {
    int nB = n + nw;
    int j0A = offA[n];
    int pdA = (deg[n] + 7) & ~7;
    int j0B = (nB < N) ? offA[nB] : 0;
    int pdB = (nB < N) ? ((deg[nB] + 7) & ~7) : 0;
    f32x2 aAL = {0.f, 0.f}, aAH = {0.f, 0.f};
    f32x2 aBL = {0.f, 0.f}, aBH = {0.f, 0.f};
    int jA = 0, jB = 0;
    for (; jA < pdA && jB < pdB; jA += 8, jB += 8) {
      FBATCH8(j0A, jA, aAL, aAH)
      FBATCH8(j0B, jB, aBL, aBH)
    }
    for (; jA < pdA; jA += 8) FBATCH8(j0A, jA, aAL, aAH)
    for (; jB < pdB; jB += 8) FBATCH8(j0B, jB, aBL, aBH)
    // slot merge: sum over 4 slots (lane^16, lane^32)
    aAL.x += __shfl_xor(aAL.x, 16); aAL.y += __shfl_xor(aAL.y, 16);
    aAH.x += __shfl_xor(aAH.x, 16); aAH.y += __shfl_xor(aAH.y, 16);
    aAL.x += __shfl_xor(aAL.x, 32); aAL.y += __shfl_xor(aAL.y, 32);
    aAH.x += __shfl_xor(aAH.x, 32); aAH.y += __shfl_xor(aAH.y, 32);
    if (slot == 0) {
      f16x4 o;
      o[0] = (_Float16)aAL.x; o[1] = (_Float16)aAL.y;
      o[2] = (_Float16)aAH.x; o[3] = (_Float16)aAH.y;
      *(f16x4*)(Sh + ((size_t)n << 6) + (q << 2)) = o;
    }
    if (nB < N) {
      aBL.x += __shfl_xor(aBL.x, 16); aBL.y += __shfl_xor(aBL.y, 16);
      aBH.x += __shfl_xor(aBH.x, 16); aBH.y += __shfl_xor(aBH.y, 16);
      aBL.x += __shfl_xor(aBL.x, 32); aBL.y += __shfl_xor(aBL.y, 32);
      aBH.x += __shfl_xor(aBH.x, 32); aBH.y += __shfl_xor(aBH.y, 32);
      if (slot == 0) {
        f16x4 o;
        o[0] = (_Float16)aBL.x; o[1] = (_Float16)aBL.y;
        o[2] = (_Float16)aBH.x; o[3] = (_Float16)aBH.y;
        *(f16x4*)(Sh + ((size_t)nB << 6) + (q << 2)) = o;
      }
    }
  }
}

// node model via MFMA + per-block stats partials (LDS reduce, non-atomic global write)
__global__ __launch_bounds__(256) void k_nodeM(const __half* __restrict__ xh,
    const __half* __restrict__ Sh, const int* __restrict__ deg,
    const __half* __restrict__ Wfrag, const float* __restrict__ c2,
    const float* __restrict__ bnode, const float* __restrict__ pa,
    __half* __restrict__ Hh, float* __restrict__ pstats, int N) {
  __shared__ float ls[128];
  const f16x8* WF = (const f16x8*)Wfrag;
  int t = threadIdx.x, lane = t & 63;
  if (t < 128) ls[t] = 0.f;
  f16x8 B[24];
#pragma unroll
  for (int f = 0; f < 24; ++f) B[f] = WF[f * 64 + lane];
  float slope = pa[0];
  int wid = (blockIdx.x * blockDim.x + t) >> 6;
  int nw = (gridDim.x * blockDim.x) >> 6;
  int ntile = N >> 4;
  int r = lane & 15, g = lane >> 4;
  float ws[4] = {0, 0, 0, 0}, wq[4] = {0, 0, 0, 0};
  __syncthreads();
  for (int tile = wid; tile < ntile; tile += nw) {
    int n0 = tile << 4;
    float dg[4];
#pragma unroll
    for (int qq = 0; qq < 4; ++qq) dg[qq] = (float)deg[n0 + g * 4 + qq];
    const f16x8* xp = (const f16x8*)(xh + (size_t)(n0 + r) * 64 + g * 8);
    const f16x8* sp = (const f16x8*)(Sh + (size_t)(n0 + r) * 64 + g * 8);
    f16x8 ax0 = xp[0], ax1 = xp[4];
    f16x8 as0 = sp[0], as1 = sp[4];
    f32x4 accA[4], accB[4];
#pragma unroll
    for (int ct = 0; ct < 4; ++ct) {
      f32x4 a = {0.f, 0.f, 0.f, 0.f};
      a = __builtin_amdgcn_mfma_f32_16x16x32_f16(ax0, B[0 + ct], a, 0, 0, 0);
      a = __builtin_amdgcn_mfma_f32_16x16x32_f16(ax1, B[4 + ct], a, 0, 0, 0);
      a = __builtin_amdgcn_mfma_f32_16x16x32_f16(as0, B[8 + ct], a, 0, 0, 0);
      a = __builtin_amdgcn_mfma_f32_16x16x32_f16(as1, B[12 + ct], a, 0, 0, 0);
      accA[ct] = a;
      f32x4 bb = {0.f, 0.f, 0.f, 0.f};
      bb = __builtin_amdgcn_mfma_f32_16x16x32_f16(ax0, B[16 + ct], bb, 0, 0, 0);
      bb = __builtin_amdgcn_mfma_f32_16x16x32_f16(ax1, B[20 + ct], bb, 0, 0, 0);
      accB[ct] = bb;
    }
#pragma unroll
    for (int ct = 0; ct < 4; ++ct) {
      int c = ct * 16 + r;
      float cc = c2[c], bv = bnode[c];
#pragma unroll
      for (int qq = 0; qq < 4; ++qq) {
        float hv = accA[ct][qq] + dg[qq] * (accB[ct][qq] + cc) + bv;
        hv = hv >= 0.f ? hv : slope * hv;
        ws[ct] += hv; wq[ct] += hv * hv;
        Hh[(size_t)(n0 + g * 4 + qq) * 64 + c] = __float2half_rn(hv);
      }
    }
  }
#pragma unroll
  for (int ct = 0; ct < 4; ++ct) {
    int c = ct * 16 + r;
    atomicAdd(&ls[c], ws[ct]);         // LDS atomics: block-local, cheap
    atomicAdd(&ls[64 + c], wq[ct]);
  }
  __syncthreads();
  if (t < 128) pstats[(size_t)blockIdx.x * 128 + t] = ls[t];
}

// reduce per-block partials (nb x 128) -> stats[128]
__global__ __launch_bounds__(256) void k_stats(const float* __restrict__ pstats,
    float* __restrict__ stats, int nb) {
  int t = threadIdx.x;
  int col = t & 127;
  int half = t >> 7;  // 0/1
  float acc = 0.f;
  for (int i = blockIdx.x * 2 + half; i < nb; i += gridDim.x * 2)
    acc += pstats[(size_t)i * 128 + col];
  atomicAdd(&stats[col], acc);
}

// BN finalize fused into the output pass
__global__ void k_out2(const __half2* __restrict__ hh, const float* __restrict__ stats,
                       const float* __restrict__ gamma, const float* __restrict__ beta,
                       float2* __restrict__ out2, int n2, float invN) {
  int i = blockIdx.x * blockDim.x + threadIdx.x;
  if (i < n2) {
    int cb = (i & 31) * 2;
    float m0 = stats[cb] * invN, m1 = stats[cb + 1] * invN;
    float v0 = stats[64 + cb] * invN - m0 * m0;
    float v1 = stats[64 + cb + 1] * invN - m1 * m1;
    float sc0 = gamma[cb] * rsqrtf(v0 + 1e-5f);
    float sc1 = gamma[cb + 1] * rsqrtf(v1 + 1e-5f);
    float sh0 = beta[cb] - m0 * sc0;
    float sh1 = beta[cb + 1] - m1 * sc1;
    __half2 v = hh[i];
    float2 o;
    o.x = __half2float(v.x) * sc0 + sh0;
    o.y = __half2float(v.y) * sc1 + sh1;
    out2[i] = o;
  }
}

// ---------------- launch ----------------

extern "C" void kernel_launch(void* const* d_in, const int* in_sizes, int n_in,
                              void* d_out, int out_size, void* d_ws, size_t ws_size,
                              hipStream_t stream) {
  const float* x     = (const float*)d_in[0];
  const int*   ei    = (const int*)d_in[1];
  const float* We    = (const float*)d_in[2];
  const float* be    = (const float*)d_in[3];
  const float* Wn    = (const float*)d_in[4];
  const float* bnode = (const float*)d_in[5];
  const float* pa    = (const float*)d_in[6];
  const float* gamma = (const float*)d_in[7];
  const float* beta  = (const float*)d_in[8];

  int N = in_sizes[0] / 64;
  int E = in_sizes[1] / 2;
  const int* srcA = ei;
  const int* dstA = ei + E;

  int NBUCK = (N + NPB - 1) / NPB;         // 391
  int FGRID = (E + FCHUNK - 1) / FCHUNK;   // 261

  char* ws = (char*)d_ws;
  size_t off = 0;
  auto alloc = [&](size_t bytes) -> void* {
    void* p = (void*)(ws + off);
    off += (bytes + 255) & ~(size_t)255;
    return p;
  };
  int ntile = N / 16;                       // 6250
  int mgrid = (ntile + 3) / 4;              // 1563 blocks -> 1 tile per wave

  float*    stats   = (float*)alloc(128 * 4);
  int*      cnt     = (int*)alloc((size_t)NBUCK * FGRID * 4);
  int*      packed2 = (int*)alloc((size_t)NBUCK * FGRID * SEGCAP * 4);  // 26 MB
  int*      csr     = (int*)alloc((size_t)NBUCK * CAP8 * 4);
  int*      offA    = (int*)alloc((size_t)N * 4);
  int*      deg     = (int*)alloc((size_t)N * 4);
  __half*   xh      = (__half*)alloc((size_t)(N + 1) * 64 * 2);  // +1 zero row
  unsigned* xq      = (unsigned*)alloc((size_t)(N + 1) * 64);    // fp8 table +1 zero row
  __half*   Sh      = (__half*)alloc((size_t)N * 64 * 2);
  __half*   Hh      = (__half*)alloc((size_t)N * 64 * 2);
  __half*   Wfrag   = (__half*)alloc((size_t)24 * 512 * 2);
  float*    c2      = (float*)alloc(64 * 4);
  float*    pstats  = (float*)alloc((size_t)mgrid * 128 * 4);

  int n4 = N * 16;
  int X2 = (n4 + 1023) / 1024;             // 1563
  int n2 = N * 32;
  int pgrid = X2 + 25 + FGRID;             // 1849

  k_prepfill<<<pgrid, 1024, 0, stream>>>(
      (const float4*)x, (__half2*)xh, xq, n4, X2,
      srcA, dstA, cnt, packed2, E, FGRID,
      We, be, Wn, Wfrag, c2, stats, NBUCK, N);
  k_sort<<<NBUCK, 1024, 0, stream>>>(packed2, cnt, csr, offA, deg, FGRID, N);
  k_agg<<<2048, 256, 0, stream>>>(xq, offA, deg, csr, Sh, N);
  k_nodeM<<<mgrid, 256, 0, stream>>>(xh, Sh, deg, Wfrag, c2, bnode, pa, Hh, pstats, N);
  k_stats<<<64, 256, 0, stream>>>(pstats, stats, mgrid);
  k_out2<<<(n2 + 255) / 256, 256, 0, stream>>>((const __half2*)Hh, stats, gamma, beta,
                                               (float2*)d_out, n2, 1.0f / (float)N);
}

// Round 20
// 115.278 us; speedup vs baseline: 1.1289x; 1.0346x over previous
//
#include <hip/hip_runtime.h>
#include <hip/hip_fp16.h>

typedef _Float16 f16x8 __attribute__((ext_vector_type(8)));
typedef _Float16 f16x4 __attribute__((ext_vector_type(4)));
typedef float f32x4 __attribute__((ext_vector_type(4)));
typedef float f32x2 __attribute__((ext_vector_type(2)));

#define NPB 128      // nodes per bucket (dst >> 7)
#define FCHUNK 6144  // edges per fill block (6 per thread @ 1024 threads)
#define SEGCAP 32    // slots per (fill-block, bucket) segment (mean 7.9, +8.6sigma<32)
#define CAPL 3584    // LDS csr capacity per bucket (mean 2048+pads, 8sigma safe)

// FUSED prep + fill. 1024-thread blocks, roles by blockIdx:
//  [0,X2): x fp32->{fp16, fp8} | [X2,X2+24): weight frags | X2+24: c2+zero-rows+stats
//  [X2+25, +FGRID): edge fill into static [bucket][fblk][SEGCAP] segments
__global__ __launch_bounds__(1024) void k_prepfill(
    const float4* __restrict__ x4, __half2* __restrict__ xh2,
    unsigned* __restrict__ xq, int n4, int X2,
    const int* __restrict__ src, const int* __restrict__ dst,
    int* __restrict__ cnt, int* __restrict__ packed2, int E, int FGRID,
    const float* __restrict__ We, const float* __restrict__ be,
    const float* __restrict__ Wn, __half* __restrict__ Wfrag, float* __restrict__ c2,
    float* __restrict__ stats, int nbuck, int N) {
  int b = blockIdx.x, t = threadIdx.x;
  if (b < X2) {
    int i = b * 1024 + t;
    if (i < n4) {
      float4 v = x4[i];
      __half2 a, c;
      a.x = __float2half_rn(v.x); a.y = __float2half_rn(v.y);
      c.x = __float2half_rn(v.z); c.y = __float2half_rn(v.w);
      xh2[2 * i] = a;
      xh2[2 * i + 1] = c;
      int w = __builtin_amdgcn_cvt_pk_fp8_f32(v.x, v.y, 0, false);
      w = __builtin_amdgcn_cvt_pk_fp8_f32(v.z, v.w, w, true);
      xq[i] = (unsigned)w;
    }
  } else if (b < X2 + 24) {
    int mb = b - X2;
    if (t < 512) {
      int mat = mb >> 3, kk = (mb >> 2) & 1, ct = mb & 3;
      int lane = t >> 3, j = t & 7;
      int k = kk * 32 + ((lane >> 4) & 3) * 8 + j;
      int col = ct * 16 + (lane & 15);
      float v;
      if (mat == 0) {
        v = Wn[k * 64 + col];
      } else if (mat == 1) {
        float a = 0.f;
        for (int m = 0; m < 64; ++m) a += We[k * 64 + m] * Wn[(64 + m) * 64 + col];
        v = a;
      } else {
        float a = 0.f;
        for (int m = 0; m < 64; ++m) a += We[(64 + k) * 64 + m] * Wn[(64 + m) * 64 + col];
        v = a;
      }
      Wfrag[mb * 512 + t] = __float2half_rn(v);
    }
  } else if (b == X2 + 24) {
    if (t < 64) {
      float a = 0.f;
      for (int m = 0; m < 64; ++m) a += be[m] * Wn[(64 + m) * 64 + t];
      c2[t] = a;
    } else if (t < 96) {
      __half2 z; z.x = __float2half_rn(0.f); z.y = __float2half_rn(0.f);
      xh2[(size_t)N * 32 + (t - 64)] = z;   // zero fp16 row N
    } else if (t < 112) {
      xq[(size_t)N * 16 + (t - 96)] = 0u;   // zero fp8 row N (pad target)
    } else if (t >= 128 && t < 256) {
      stats[t - 128] = 0.f;
    }
  } else {
    int fb = b - (X2 + 25);
    __shared__ int lh[1024];
    int e0 = fb * FCHUNK;
    int e1 = min(e0 + FCHUNK, E);
    lh[t] = 0;
    __syncthreads();
    int dv[6];
#pragma unroll
    for (int i = 0; i < 6; ++i) {
      int e = e0 + t + i * 1024;
      dv[i] = (e < e1) ? dst[e] : -1;
      if (dv[i] >= 0) atomicAdd(&lh[dv[i] >> 7], 1);
    }
    __syncthreads();
    if (t < nbuck) cnt[(size_t)t * FGRID + fb] = lh[t];  // non-atomic count
    lh[t] = 0;  // reuse as local cursor
    __syncthreads();
#pragma unroll
    for (int i = 0; i < 6; ++i) {
      int d = dv[i];
      if (d >= 0) {
        int e = e0 + t + i * 1024;
        int bk = d >> 7;
        unsigned lp = (unsigned)atomicAdd(&lh[bk], 1);
        if (lp < SEGCAP)
          packed2[((size_t)bk * FGRID + fb) * SEGCAP + lp] = src[e] | ((d & 127) << 20);
      }
    }
  }
}

// one 8-edge batch: 8 LDS csr reads (broadcast), slot-select 2 edges,
// 2 dword fp8 gathers (4 feats each), HW cvt, f32 accumulate.
#define LBATCH8(J0, J, AL, AH)                                                 \
  {                                                                            \
    int u_ = (J0) + (J);                                                       \
    int e0_ = csrL[u_ + 0], e1_ = csrL[u_ + 1], e2_ = csrL[u_ + 2], e3_ = csrL[u_ + 3]; \
    int e4_ = csrL[u_ + 4], e5_ = csrL[u_ + 5], e6_ = csrL[u_ + 6], e7_ = csrL[u_ + 7]; \
    int p1_ = (slot & 1) ? e1_ : e0_, q1_ = (slot & 1) ? e3_ : e2_;            \
    int s1_ = (slot & 2) ? q1_ : p1_;                                          \
    int p2_ = (slot & 1) ? e5_ : e4_, q2_ = (slot & 1) ? e7_ : e6_;            \
    int s2_ = (slot & 2) ? q2_ : p2_;                                          \
    unsigned w1_ = xq[((unsigned)s1_ << 4) | q];                               \
    unsigned w2_ = xq[((unsigned)s2_ << 4) | q];                               \
    f32x2 l1_ = __builtin_amdgcn_cvt_pk_f32_fp8(w1_, false);                   \
    f32x2 h1_ = __builtin_amdgcn_cvt_pk_f32_fp8(w1_, true);                    \
    f32x2 l2_ = __builtin_amdgcn_cvt_pk_f32_fp8(w2_, false);                   \
    f32x2 h2_ = __builtin_amdgcn_cvt_pk_f32_fp8(w2_, true);                    \
    AL += l1_; AH += h1_; AL += l2_; AH += h2_;                                \
  }

// FUSED counting sort (CSR in LDS) + aggregation. One block per 128-node bucket.
__global__ __launch_bounds__(512) void k_sortagg(
    const int* __restrict__ packed2, const int* __restrict__ cnt,
    const unsigned* __restrict__ xq, int* __restrict__ deg,
    __half* __restrict__ Sh, int FGRID, int N) {
  __shared__ int scnt[264];
  __shared__ int hist[NPB];
  __shared__ int sc[NPB];
  __shared__ int curs[NPB];
  __shared__ int csrL[CAPL];
  int b = blockIdx.x, t = threadIdx.x;
  if (t < NPB) hist[t] = 0;
  for (int i = t; i < FGRID; i += 512) scnt[i] = cnt[(size_t)b * FGRID + i];
  __syncthreads();
  int slots = FGRID * SEGCAP;
  const int* seg = packed2 + (size_t)b * FGRID * SEGCAP;
  for (int idx = t; idx < slots; idx += 512) {
    int s = idx >> 5, k = idx & 31;
    if (k < scnt[s]) atomicAdd(&hist[(seg[idx] >> 20) & 127], 1);
  }
  __syncthreads();
  int v = (t < NPB) ? hist[t] : 0;
  int pv = (v + 7) & ~7;       // padded degree
  if (t < NPB) sc[t] = pv;
  __syncthreads();
  for (int d = 1; d < NPB; d <<= 1) {
    int a = (t >= d && t < NPB) ? sc[t - d] : 0;
    __syncthreads();
    if (t < NPB) sc[t] += a;
    __syncthreads();
  }
  if (t < NPB) {
    int ex = sc[t] - pv;       // local CSR start
    curs[t] = ex;
    int n = b * NPB + t;
    if (n < N) deg[n] = v;
    for (int k = v; k < pv; ++k) csrL[ex + k] = N;  // pads -> zero row
  }
  __syncthreads();
  for (int idx = t; idx < slots; idx += 512) {
    int s = idx >> 5, k = idx & 31;
    if (k < scnt[s]) {
      int pk = seg[idx];
      int p = atomicAdd(&curs[(pk >> 20) & 127], 1);
      csrL[p] = pk & 0xFFFFF;
    }
  }
  __syncthreads();
  // ---- aggregation: wave w owns local nodes [w*16, w*16+16), dual-interleaved
  int w = t >> 6;
  unsigned lane = t & 63;
  unsigned q = lane & 15;          // feature quad
  int slot = (int)(lane >> 4);     // 0..3
  for (int p = 0; p < 16; p += 2) {
    int ln = w * 16 + p;
    int vA = hist[ln], vB = hist[ln + 1];
    int pdA = (vA + 7) & ~7, pdB = (vB + 7) & ~7;
    int j0A = sc[ln] - pdA, j0B = sc[ln + 1] - pdB;
    f32x2 aAL = {0.f, 0.f}, aAH = {0.f, 0.f};
    f32x2 aBL = {0.f, 0.f}, aBH = {0.f, 0.f};
    int jA = 0, jB = 0;
    for (; jA < pdA && jB < pdB; jA += 8, jB += 8) {
      LBATCH8(j0A, jA, aAL, aAH)
      LBATCH8(j0B, jB, aBL, aBH)
    }
    for (; jA < pdA; jA += 8) LBATCH8(j0A, jA, aAL, aAH)
    for (; jB < pdB; jB += 8) LBATCH8(j0B, jB, aBL, aBH)
    aAL.x += __shfl_xor(aAL.x, 16); aAL.y += __shfl_xor(aAL.y, 16);
    aAH.x += __shfl_xor(aAH.x, 16); aAH.y += __shfl_xor(aAH.y, 16);
    aAL.x += __shfl_xor(aAL.x, 32); aAL.y += __shfl_xor(aAL.y, 32);
    aAH.x += __shfl_xor(aAH.x, 32); aAH.y += __shfl_xor(aAH.y, 32);
    aBL.x += __shfl_xor(aBL.x, 16); aBL.y += __shfl_xor(aBL.y, 16);
    aBH.x += __shfl_xor(aBH.x, 16); aBH.y += __shfl_xor(aBH.y, 16);
    aBL.x += __shfl_xor(aBL.x, 32); aBL.y += __shfl_xor(aBL.y, 32);
    aBH.x += __shfl_xor(aBH.x, 32); aBH.y += __shfl_xor(aBH.y, 32);
    int n = b * NPB + ln;
    if (slot == 0) {
      if (n < N) {
        f16x4 o;
        o[0] = (_Float16)aAL.x; o[1] = (_Float16)aAL.y;
        o[2] = (_Float16)aAH.x; o[3] = (_Float16)aAH.y;
        *(f16x4*)(Sh + ((size_t)n << 6) + (q << 2)) = o;
      }
      if (n + 1 < N) {
        f16x4 o;
        o[0] = (_Float16)aBL.x; o[1] = (_Float16)aBL.y;
        o[2] = (_Float16)aBH.x; o[3] = (_Float16)aBH.y;
        *(f16x4*)(Sh + ((size_t)(n + 1) << 6) + (q << 2)) = o;
      }
    }
  }
}

// node model via MFMA + per-block stats partials (LDS reduce, non-atomic global write)
__global__ __launch_bounds__(256) void k_nodeM(const __half* __restrict__ xh,
    const __half* __restrict__ Sh, const int* __restrict__ deg,
    const __half* __restrict__ Wfrag, const float* __restrict__ c2,
    const float* __restrict__ bnode, const float* __restrict__ pa,
    __half* __restrict__ Hh, float* __restrict__ pstats, int N) {
  __shared__ float ls[128];
  const f16x8* WF = (const f16x8*)Wfrag;
  int t = threadIdx.x, lane = t & 63;
  if (t < 128) ls[t] = 0.f;
  f16x8 B[24];
#pragma unroll
  for (int f = 0; f < 24; ++f) B[f] = WF[f * 64 + lane];
  float slope = pa[0];
  int wid = (blockIdx.x * blockDim.x + t) >> 6;
  int nw = (gridDim.x * blockDim.x) >> 6;
  int ntile = N >> 4;
  int r = lane & 15, g = lane >> 4;
  float ws[4] = {0, 0, 0, 0}, wq[4] = {0, 0, 0, 0};
  __syncthreads();
  for (int tile = wid; tile < ntile; tile += nw) {
    int n0 = tile << 4;
    float dg[4];
#pragma unroll
    for (int qq = 0; qq < 4; ++qq) dg[qq] = (float)deg[n0 + g * 4 + qq];
    const f16x8* xp = (const f16x8*)(xh + (size_t)(n0 + r) * 64 + g * 8);
    const f16x8* sp = (const f16x8*)(Sh + (size_t)(n0 + r) * 64 + g * 8);
    f16x8 ax0 = xp[0], ax1 = xp[4];
    f16x8 as0 = sp[0], as1 = sp[4];
    f32x4 accA[4], accB[4];
#pragma unroll
    for (int ct = 0; ct < 4; ++ct) {
      f32x4 a = {0.f, 0.f, 0.f, 0.f};
      a = __builtin_amdgcn_mfma_f32_16x16x32_f16(ax0, B[0 + ct], a, 0, 0, 0);
      a = __builtin_amdgcn_mfma_f32_16x16x32_f16(ax1, B[4 + ct], a, 0, 0, 0);
      a = __builtin_amdgcn_mfma_f32_16x16x32_f16(as0, B[8 + ct], a, 0, 0, 0);
      a = __builtin_amdgcn_mfma_f32_16x16x32_f16(as1, B[12 + ct], a, 0, 0, 0);
      accA[ct] = a;
      f32x4 bb = {0.f, 0.f, 0.f, 0.f};
      bb = __builtin_amdgcn_mfma_f32_16x16x32_f16(ax0, B[16 + ct], bb, 0, 0, 0);
      bb = __builtin_amdgcn_mfma_f32_16x16x32_f16(ax1, B[20 + ct], bb, 0, 0, 0);
      accB[ct] = bb;
    }
#pragma unroll
    for (int ct = 0; ct < 4; ++ct) {
      int c = ct * 16 + r;
      float cc = c2[c], bv = bnode[c];
#pragma unroll
      for (int qq = 0; qq < 4; ++qq) {
        float hv = accA[ct][qq] + dg[qq] * (accB[ct][qq] + cc) + bv;
        hv = hv >= 0.f ? hv : slope * hv;
        ws[ct] += hv; wq[ct] += hv * hv;
        Hh[(size_t)(n0 + g * 4 + qq) * 64 + c] = __float2half_rn(hv);
      }
    }
  }
#pragma unroll
  for (int ct = 0; ct < 4; ++ct) {
    int c = ct * 16 + r;
    atomicAdd(&ls[c], ws[ct]);
    atomicAdd(&ls[64 + c], wq[ct]);
  }
  __syncthreads();
  if (t < 128) pstats[(size_t)blockIdx.x * 128 + t] = ls[t];
}

// reduce per-block partials (nb x 128) -> stats[128]
__global__ __launch_bounds__(256) void k_stats(const float* __restrict__ pstats,
    float* __restrict__ stats, int nb) {
  int t = threadIdx.x;
  int col = t & 127;
  int half = t >> 7;  // 0/1
  float acc = 0.f;
  for (int i = blockIdx.x * 2 + half; i < nb; i += gridDim.x * 2)
    acc += pstats[(size_t)i * 128 + col];
  atomicAdd(&stats[col], acc);
}

// BN finalize fused into the output pass
__global__ void k_out2(const __half2* __restrict__ hh, const float* __restrict__ stats,
                       const float* __restrict__ gamma, const float* __restrict__ beta,
                       float2* __restrict__ out2, int n2, float invN) {
  int i = blockIdx.x * blockDim.x + threadIdx.x;
  if (i < n2) {
    int cb = (i & 31) * 2;
    float m0 = stats[cb] * invN, m1 = stats[cb + 1] * invN;
    float v0 = stats[64 + cb] * invN - m0 * m0;
    float v1 = stats[64 + cb + 1] * invN - m1 * m1;
    float sc0 = gamma[cb] * rsqrtf(v0 + 1e-5f);
    float sc1 = gamma[cb + 1] * rsqrtf(v1 + 1e-5f);
    float sh0 = beta[cb] - m0 * sc0;
    float sh1 = beta[cb + 1] - m1 * sc1;
    __half2 v = hh[i];
    float2 o;
    o.x = __half2float(v.x) * sc0 + sh0;
    o.y = __half2float(v.y) * sc1 + sh1;
    out2[i] = o;
  }
}

// ---------------- launch ----------------

extern "C" void kernel_launch(void* const* d_in, const int* in_sizes, int n_in,
                              void* d_out, int out_size, void* d_ws, size_t ws_size,
                              hipStream_t stream) {
  const float* x     = (const float*)d_in[0];
  const int*   ei    = (const int*)d_in[1];
  const float* We    = (const float*)d_in[2];
  const float* be    = (const float*)d_in[3];
  const float* Wn    = (const float*)d_in[4];
  const float* bnode = (const float*)d_in[5];
  const float* pa    = (const float*)d_in[6];
  const float* gamma = (const float*)d_in[7];
  const float* beta  = (const float*)d_in[8];

  int N = in_sizes[0] / 64;
  int E = in_sizes[1] / 2;
  const int* srcA = ei;
  const int* dstA = ei + E;

  int NBUCK = (N + NPB - 1) / NPB;         // 782
  int FGRID = (E + FCHUNK - 1) / FCHUNK;   // 261

  char* ws = (char*)d_ws;
  size_t off = 0;
  auto alloc = [&](size_t bytes) -> void* {
    void* p = (void*)(ws + off);
    off += (bytes + 255) & ~(size_t)255;
    return p;
  };
  int ntile = N / 16;                       // 6250
  int mgrid = (ntile + 3) / 4;              // 1563 blocks -> 1 tile per wave

  float*    stats   = (float*)alloc(128 * 4);
  int*      cnt     = (int*)alloc((size_t)NBUCK * FGRID * 4);
  int*      packed2 = (int*)alloc((size_t)NBUCK * FGRID * SEGCAP * 4);  // 26 MB
  int*      deg     = (int*)alloc((size_t)N * 4);
  __half*   xh      = (__half*)alloc((size_t)(N + 1) * 64 * 2);  // +1 zero row
  unsigned* xq      = (unsigned*)alloc((size_t)(N + 1) * 64);    // fp8 table +1 zero row
  __half*   Sh      = (__half*)alloc((size_t)N * 64 * 2);
  __half*   Hh      = (__half*)alloc((size_t)N * 64 * 2);
  __half*   Wfrag   = (__half*)alloc((size_t)24 * 512 * 2);
  float*    c2      = (float*)alloc(64 * 4);
  float*    pstats  = (float*)alloc((size_t)mgrid * 128 * 4);

  int n4 = N * 16;
  int X2 = (n4 + 1023) / 1024;             // 1563
  int n2 = N * 32;
  int pgrid = X2 + 25 + FGRID;             // 1849

  k_prepfill<<<pgrid, 1024, 0, stream>>>(
      (const float4*)x, (__half2*)xh, xq, n4, X2,
      srcA, dstA, cnt, packed2, E, FGRID,
      We, be, Wn, Wfrag, c2, stats, NBUCK, N);
  k_sortagg<<<NBUCK, 512, 0, stream>>>(packed2, cnt, xq, deg, Sh, FGRID, N);
  k_nodeM<<<mgrid, 256, 0, stream>>>(xh, Sh, deg, Wfrag, c2, bnode, pa, Hh, pstats, N);
  k_stats<<<64, 256, 0, stream>>>(pstats, stats, mgrid);
  k_out2<<<(n2 + 255) / 256, 256, 0, stream>>>((const __half2*)Hh, stats, gamma, beta,
                                               (float2*)d_out, n2, 1.0f / (float)N);
}

// Round 21
// 112.540 us; speedup vs baseline: 1.1563x; 1.0243x over previous
//
#include <hip/hip_runtime.h>
#include <hip/hip_fp16.h>

typedef _Float16 f16x8 __attribute__((ext_vector_type(8)));
typedef _Float16 f16x4 __attribute__((ext_vector_type(4)));
typedef float f32x4 __attribute__((ext_vector_type(4)));
typedef float f32x2 __attribute__((ext_vector_type(2)));

#define NPB 128      // nodes per bucket (dst >> 7)
#define FCHUNK 6144  // edges per fill block (6 per thread @ 1024 threads)
#define SEGCAP 32    // slots per (fill-block, bucket) segment (mean 7.9, +8.6sigma<32)
#define CAPL 3584    // LDS csr capacity per bucket (mean 2048+pads, 8sigma safe)
#define STAGECAP 4096 // LDS staging capacity (mean 2048, sigma 45)

// FUSED prep + fill. 1024-thread blocks, roles by blockIdx:
//  [0,X2): x fp32->{fp16, fp8} | [X2,X2+24): weight frags | X2+24: c2+zero-rows+stats
//  [X2+25, +FGRID): edge fill into static [bucket][fblk][SEGCAP] segments
__global__ __launch_bounds__(1024) void k_prepfill(
    const float4* __restrict__ x4, __half2* __restrict__ xh2,
    unsigned* __restrict__ xq, int n4, int X2,
    const int* __restrict__ src, const int* __restrict__ dst,
    int* __restrict__ cnt, int* __restrict__ packed2, int E, int FGRID,
    const float* __restrict__ We, const float* __restrict__ be,
    const float* __restrict__ Wn, __half* __restrict__ Wfrag, float* __restrict__ c2,
    float* __restrict__ stats, int nbuck, int N) {
  int b = blockIdx.x, t = threadIdx.x;
  if (b < X2) {
    int i = b * 1024 + t;
    if (i < n4) {
      float4 v = x4[i];
      __half2 a, c;
      a.x = __float2half_rn(v.x); a.y = __float2half_rn(v.y);
      c.x = __float2half_rn(v.z); c.y = __float2half_rn(v.w);
      xh2[2 * i] = a;
      xh2[2 * i + 1] = c;
      int w = __builtin_amdgcn_cvt_pk_fp8_f32(v.x, v.y, 0, false);
      w = __builtin_amdgcn_cvt_pk_fp8_f32(v.z, v.w, w, true);
      xq[i] = (unsigned)w;
    }
  } else if (b < X2 + 24) {
    int mb = b - X2;
    if (t < 512) {
      int mat = mb >> 3, kk = (mb >> 2) & 1, ct = mb & 3;
      int lane = t >> 3, j = t & 7;
      int k = kk * 32 + ((lane >> 4) & 3) * 8 + j;
      int col = ct * 16 + (lane & 15);
      float v;
      if (mat == 0) {
        v = Wn[k * 64 + col];
      } else if (mat == 1) {
        float a = 0.f;
        for (int m = 0; m < 64; ++m) a += We[k * 64 + m] * Wn[(64 + m) * 64 + col];
        v = a;
      } else {
        float a = 0.f;
        for (int m = 0; m < 64; ++m) a += We[(64 + k) * 64 + m] * Wn[(64 + m) * 64 + col];
        v = a;
      }
      Wfrag[mb * 512 + t] = __float2half_rn(v);
    }
  } else if (b == X2 + 24) {
    if (t < 64) {
      float a = 0.f;
      for (int m = 0; m < 64; ++m) a += be[m] * Wn[(64 + m) * 64 + t];
      c2[t] = a;
    } else if (t < 96) {
      __half2 z; z.x = __float2half_rn(0.f); z.y = __float2half_rn(0.f);
      xh2[(size_t)N * 32 + (t - 64)] = z;   // zero fp16 row N
    } else if (t < 112) {
      xq[(size_t)N * 16 + (t - 96)] = 0u;   // zero fp8 row N (pad target)
    } else if (t >= 128 && t < 256) {
      stats[t - 128] = 0.f;
    }
  } else {
    int fb = b - (X2 + 25);
    __shared__ int lh[1024];
    int e0 = fb * FCHUNK;
    int e1 = min(e0 + FCHUNK, E);
    lh[t] = 0;
    __syncthreads();
    int dv[6];
#pragma unroll
    for (int i = 0; i < 6; ++i) {
      int e = e0 + t + i * 1024;
      dv[i] = (e < e1) ? dst[e] : -1;
      if (dv[i] >= 0) atomicAdd(&lh[dv[i] >> 7], 1);
    }
    __syncthreads();
    if (t < nbuck) cnt[(size_t)t * FGRID + fb] = lh[t];  // non-atomic count
    lh[t] = 0;  // reuse as local cursor
    __syncthreads();
#pragma unroll
    for (int i = 0; i < 6; ++i) {
      int d = dv[i];
      if (d >= 0) {
        int e = e0 + t + i * 1024;
        int bk = d >> 7;
        unsigned lp = (unsigned)atomicAdd(&lh[bk], 1);
        if (lp < SEGCAP)
          packed2[((size_t)bk * FGRID + fb) * SEGCAP + lp] = src[e] | ((d & 127) << 20);
      }
    }
  }
}

// one 8-edge batch: 8 LDS csr reads (broadcast), slot-select 2 edges,
// 2 dword fp8 gathers (4 feats each), HW cvt, f32 accumulate.
#define LBATCH8(J0, J, AL, AH)                                                 \
  {                                                                            \
    int u_ = (J0) + (J);                                                       \
    int e0_ = csrL[u_ + 0], e1_ = csrL[u_ + 1], e2_ = csrL[u_ + 2], e3_ = csrL[u_ + 3]; \
    int e4_ = csrL[u_ + 4], e5_ = csrL[u_ + 5], e6_ = csrL[u_ + 6], e7_ = csrL[u_ + 7]; \
    int p1_ = (slot & 1) ? e1_ : e0_, q1_ = (slot & 1) ? e3_ : e2_;            \
    int s1_ = (slot & 2) ? q1_ : p1_;                                          \
    int p2_ = (slot & 1) ? e5_ : e4_, q2_ = (slot & 1) ? e7_ : e6_;            \
    int s2_ = (slot & 2) ? q2_ : p2_;                                          \
    unsigned w1_ = xq[((unsigned)s1_ << 4) | q];                               \
    unsigned w2_ = xq[((unsigned)s2_ << 4) | q];                               \
    f32x2 l1_ = __builtin_amdgcn_cvt_pk_f32_fp8(w1_, false);                   \
    f32x2 h1_ = __builtin_amdgcn_cvt_pk_f32_fp8(w1_, true);                    \
    f32x2 l2_ = __builtin_amdgcn_cvt_pk_f32_fp8(w2_, false);                   \
    f32x2 h2_ = __builtin_amdgcn_cvt_pk_f32_fp8(w2_, true);                    \
    AL += l1_; AH += h1_; AL += l2_; AH += h2_;                                \
  }

// FUSED counting sort (CSR in LDS) + aggregation. SINGLE global pass:
// segments -> LDS stage (+hist) -> scan -> LDS scatter -> aggregate.
__global__ __launch_bounds__(512) void k_sortagg(
    const int* __restrict__ packed2, const int* __restrict__ cnt,
    const unsigned* __restrict__ xq, int* __restrict__ deg,
    __half* __restrict__ Sh, int FGRID, int N) {
  __shared__ int scnt[264];
  __shared__ int hist[NPB];
  __shared__ int sc[NPB];
  __shared__ int curs[NPB];
  __shared__ int stage[STAGECAP];
  __shared__ int csrL[CAPL];
  __shared__ int nstage_;
  int b = blockIdx.x, t = threadIdx.x;
  if (t < NPB) hist[t] = 0;
  if (t == 0) nstage_ = 0;
  for (int i = t; i < FGRID; i += 512) scnt[i] = cnt[(size_t)b * FGRID + i];
  __syncthreads();
  int slots = FGRID * SEGCAP;
  const int* seg = packed2 + (size_t)b * FGRID * SEGCAP;
  for (int idx = t; idx < slots; idx += 512) {
    int s = idx >> 5, k = idx & 31;
    if (k < scnt[s]) {
      int pk = seg[idx];
      int p = atomicAdd(&nstage_, 1);
      if (p < STAGECAP) {
        stage[p] = pk;
        atomicAdd(&hist[(pk >> 20) & 127], 1);
      }
    }
  }
  __syncthreads();
  int v = (t < NPB) ? hist[t] : 0;
  int pv = (v + 7) & ~7;       // padded degree
  if (t < NPB) sc[t] = pv;
  __syncthreads();
  for (int d = 1; d < NPB; d <<= 1) {
    int a = (t >= d && t < NPB) ? sc[t - d] : 0;
    __syncthreads();
    if (t < NPB) sc[t] += a;
    __syncthreads();
  }
  if (t < NPB) {
    int ex = sc[t] - pv;       // local CSR start
    curs[t] = ex;
    int n = b * NPB + t;
    if (n < N) deg[n] = v;
    for (int k = v; k < pv; ++k) csrL[ex + k] = N;  // pads -> zero row
  }
  __syncthreads();
  int tot = nstage_ < STAGECAP ? nstage_ : STAGECAP;
  for (int idx = t; idx < tot; idx += 512) {
    int pk = stage[idx];
    int p = atomicAdd(&curs[(pk >> 20) & 127], 1);
    csrL[p] = pk & 0xFFFFF;
  }
  __syncthreads();
  // ---- aggregation: wave w owns local nodes [w*16, w*16+16), dual-interleaved
  int w = t >> 6;
  unsigned lane = t & 63;
  unsigned q = lane & 15;          // feature quad
  int slot = (int)(lane >> 4);     // 0..3
  for (int p = 0; p < 16; p += 2) {
    int ln = w * 16 + p;
    int vA = hist[ln], vB = hist[ln + 1];
    int pdA = (vA + 7) & ~7, pdB = (vB + 7) & ~7;
    int j0A = sc[ln] - pdA, j0B = sc[ln + 1] - pdB;
    f32x2 aAL = {0.f, 0.f}, aAH = {0.f, 0.f};
    f32x2 aBL = {0.f, 0.f}, aBH = {0.f, 0.f};
    int jA = 0, jB = 0;
    for (; jA < pdA && jB < pdB; jA += 8, jB += 8) {
      LBATCH8(j0A, jA, aAL, aAH)
      LBATCH8(j0B, jB, aBL, aBH)
    }
    for (; jA < pdA; jA += 8) LBATCH8(j0A, jA, aAL, aAH)
    for (; jB < pdB; jB += 8) LBATCH8(j0B, jB, aBL, aBH)
    aAL.x += __shfl_xor(aAL.x, 16); aAL.y += __shfl_xor(aAL.y, 16);
    aAH.x += __shfl_xor(aAH.x, 16); aAH.y += __shfl_xor(aAH.y, 16);
    aAL.x += __shfl_xor(aAL.x, 32); aAL.y += __shfl_xor(aAL.y, 32);
    aAH.x += __shfl_xor(aAH.x, 32); aAH.y += __shfl_xor(aAH.y, 32);
    aBL.x += __shfl_xor(aBL.x, 16); aBL.y += __shfl_xor(aBL.y, 16);
    aBH.x += __shfl_xor(aBH.x, 16); aBH.y += __shfl_xor(aBH.y, 16);
    aBL.x += __shfl_xor(aBL.x, 32); aBL.y += __shfl_xor(aBL.y, 32);
    aBH.x += __shfl_xor(aBH.x, 32); aBH.y += __shfl_xor(aBH.y, 32);
    int n = b * NPB + ln;
    if (slot == 0) {
      if (n < N) {
        f16x4 o;
        o[0] = (_Float16)aAL.x; o[1] = (_Float16)aAL.y;
        o[2] = (_Float16)aAH.x; o[3] = (_Float16)aAH.y;
        *(f16x4*)(Sh + ((size_t)n << 6) + (q << 2)) = o;
      }
      if (n + 1 < N) {
        f16x4 o;
        o[0] = (_Float16)aBL.x; o[1] = (_Float16)aBL.y;
        o[2] = (_Float16)aBH.x; o[3] = (_Float16)aBH.y;
        *(f16x4*)(Sh + ((size_t)(n + 1) << 6) + (q << 2)) = o;
      }
    }
  }
}

// node model via MFMA + per-block stats partials (LDS reduce, non-atomic global write)
__global__ __launch_bounds__(256) void k_nodeM(const __half* __restrict__ xh,
    const __half* __restrict__ Sh, const int* __restrict__ deg,
    const __half* __restrict__ Wfrag, const float* __restrict__ c2,
    const float* __restrict__ bnode, const float* __restrict__ pa,
    __half* __restrict__ Hh, float* __restrict__ pstats, int N) {
  __shared__ float ls[128];
  const f16x8* WF = (const f16x8*)Wfrag;
  int t = threadIdx.x, lane = t & 63;
  if (t < 128) ls[t] = 0.f;
  f16x8 B[24];
#pragma unroll
  for (int f = 0; f < 24; ++f) B[f] = WF[f * 64 + lane];
  float slope = pa[0];
  int wid = (blockIdx.x * blockDim.x + t) >> 6;
  int nw = (gridDim.x * blockDim.x) >> 6;
  int ntile = N >> 4;
  int r = lane & 15, g = lane >> 4;
  float ws[4] = {0, 0, 0, 0}, wq[4] = {0, 0, 0, 0};
  __syncthreads();
  for (int tile = wid; tile < ntile; tile += nw) {
    int n0 = tile << 4;
    float dg[4];
#pragma unroll
    for (int qq = 0; qq < 4; ++qq) dg[qq] = (float)deg[n0 + g * 4 + qq];
    const f16x8* xp = (const f16x8*)(xh + (size_t)(n0 + r) * 64 + g * 8);
    const f16x8* sp = (const f16x8*)(Sh + (size_t)(n0 + r) * 64 + g * 8);
    f16x8 ax0 = xp[0], ax1 = xp[4];
    f16x8 as0 = sp[0], as1 = sp[4];
    f32x4 accA[4], accB[4];
#pragma unroll
    for (int ct = 0; ct < 4; ++ct) {
      f32x4 a = {0.f, 0.f, 0.f, 0.f};
      a = __builtin_amdgcn_mfma_f32_16x16x32_f16(ax0, B[0 + ct], a, 0, 0, 0);
      a = __builtin_amdgcn_mfma_f32_16x16x32_f16(ax1, B[4 + ct], a, 0, 0, 0);
      a = __builtin_amdgcn_mfma_f32_16x16x32_f16(as0, B[8 + ct], a, 0, 0, 0);
      a = __builtin_amdgcn_mfma_f32_16x16x32_f16(as1, B[12 + ct], a, 0, 0, 0);
      accA[ct] = a;
      f32x4 bb = {0.f, 0.f, 0.f, 0.f};
      bb = __builtin_amdgcn_mfma_f32_16x16x32_f16(ax0, B[16 + ct], bb, 0, 0, 0);
      bb = __builtin_amdgcn_mfma_f32_16x16x32_f16(ax1, B[20 + ct], bb, 0, 0, 0);
      accB[ct] = bb;
    }
#pragma unroll
    for (int ct = 0; ct < 4; ++ct) {
      int c = ct * 16 + r;
      float cc = c2[c], bv = bnode[c];
#pragma unroll
      for (int qq = 0; qq < 4; ++qq) {
        float hv = accA[ct][qq] + dg[qq] * (accB[ct][qq] + cc) + bv;
        hv = hv >= 0.f ? hv : slope * hv;
        ws[ct] += hv; wq[ct] += hv * hv;
        Hh[(size_t)(n0 + g * 4 + qq) * 64 + c] = __float2half_rn(hv);
      }
    }
  }
#pragma unroll
  for (int ct = 0; ct < 4; ++ct) {
    int c = ct * 16 + r;
    atomicAdd(&ls[c], ws[ct]);
    atomicAdd(&ls[64 + c], wq[ct]);
  }
  __syncthreads();
  if (t < 128) pstats[(size_t)blockIdx.x * 128 + t] = ls[t];
}

// reduce per-block partials (nb x 128) -> stats[128]
__global__ __launch_bounds__(256) void k_stats(const float* __restrict__ pstats,
    float* __restrict__ stats, int nb) {
  int t = threadIdx.x;
  int col = t & 127;
  int half = t >> 7;  // 0/1
  float acc = 0.f;
  for (int i = blockIdx.x * 2 + half; i < nb; i += gridDim.x * 2)
    acc += pstats[(size_t)i * 128 + col];
  atomicAdd(&stats[col], acc);
}

// BN finalize fused into the output pass
__global__ void k_out2(const __half2* __restrict__ hh, const float* __restrict__ stats,
                       const float* __restrict__ gamma, const float* __restrict__ beta,
                       float2* __restrict__ out2, int n2, float invN) {
  int i = blockIdx.x * blockDim.x + threadIdx.x;
  if (i < n2) {
    int cb = (i & 31) * 2;
    float m0 = stats[cb] * invN, m1 = stats[cb + 1] * invN;
    float v0 = stats[64 + cb] * invN - m0 * m0;
    float v1 = stats[64 + cb + 1] * invN - m1 * m1;
    float sc0 = gamma[cb] * rsqrtf(v0 + 1e-5f);
    float sc1 = gamma[cb + 1] * rsqrtf(v1 + 1e-5f);
    float sh0 = beta[cb] - m0 * sc0;
    float sh1 = beta[cb + 1] - m1 * sc1;
    __half2 v = hh[i];
    float2 o;
    o.x = __half2float(v.x) * sc0 + sh0;
    o.y = __half2float(v.y) * sc1 + sh1;
    out2[i] = o;
  }
}

// ---------------- launch ----------------

extern "C" void kernel_launch(void* const* d_in, const int* in_sizes, int n_in,
                              void* d_out, int out_size, void* d_ws, size_t ws_size,
                              hipStream_t stream) {
  const float* x     = (const float*)d_in[0];
  const int*   ei    = (const int*)d_in[1];
  const float* We    = (const float*)d_in[2];
  const float* be    = (const float*)d_in[3];
  const float* Wn    = (const float*)d_in[4];
  const float* bnode = (const float*)d_in[5];
  const float* pa    = (const float*)d_in[6];
  const float* gamma = (const float*)d_in[7];
  const float* beta  = (const float*)d_in[8];

  int N = in_sizes[0] / 64;
  int E = in_sizes[1] / 2;
  const int* srcA = ei;
  const int* dstA = ei + E;

  int NBUCK = (N + NPB - 1) / NPB;         // 782
  int FGRID = (E + FCHUNK - 1) / FCHUNK;   // 261

  char* ws = (char*)d_ws;
  size_t off = 0;
  auto alloc = [&](size_t bytes) -> void* {
    void* p = (void*)(ws + off);
    off += (bytes + 255) & ~(size_t)255;
    return p;
  };
  int ntile = N / 16;                       // 6250
  int mgrid = (ntile + 3) / 4;              // 1563 blocks -> 1 tile per wave

  float*    stats   = (float*)alloc(128 * 4);
  int*      cnt     = (int*)alloc((size_t)NBUCK * FGRID * 4);
  int*      packed2 = (int*)alloc((size_t)NBUCK * FGRID * SEGCAP * 4);  // 26 MB
  int*      deg     = (int*)alloc((size_t)N * 4);
  __half*   xh      = (__half*)alloc((size_t)(N + 1) * 64 * 2);  // +1 zero row
  unsigned* xq      = (unsigned*)alloc((size_t)(N + 1) * 64);    // fp8 table +1 zero row
  __half*   Sh      = (__half*)alloc((size_t)N * 64 * 2);
  __half*   Hh      = (__half*)alloc((size_t)N * 64 * 2);
  __half*   Wfrag   = (__half*)alloc((size_t)24 * 512 * 2);
  float*    c2      = (float*)alloc(64 * 4);
  float*    pstats  = (float*)alloc((size_t)mgrid * 128 * 4);

  int n4 = N * 16;
  int X2 = (n4 + 1023) / 1024;             // 1563
  int n2 = N * 32;
  int pgrid = X2 + 25 + FGRID;             // 1849

  k_prepfill<<<pgrid, 1024, 0, stream>>>(
      (const float4*)x, (__half2*)xh, xq, n4, X2,
      srcA, dstA, cnt, packed2, E, FGRID,
      We, be, Wn, Wfrag, c2, stats, NBUCK, N);
  k_sortagg<<<NBUCK, 512, 0, stream>>>(packed2, cnt, xq, deg, Sh, FGRID, N);
  k_nodeM<<<mgrid, 256, 0, stream>>>(xh, Sh, deg, Wfrag, c2, bnode, pa, Hh, pstats, N);
  k_stats<<<64, 256, 0, stream>>>(pstats, stats, mgrid);
  k_out2<<<(n2 + 255) / 256, 256, 0, stream>>>((const __half2*)Hh, stats, gamma, beta,
                                               (float2*)d_out, n2, 1.0f / (float)N);
}